// Round 4
// baseline (4065.805 us; speedup 1.0000x reference)
//
#include <hip/hip_runtime.h>
#include <math.h>

// CGConv: N=100000 atoms, M=12 nbrs, F=64 atom-feat, B=41 bond-feat
// gated = [self | nbr | bond] @ W + b ; BN1 over N*M rows ;
// summed = sum_j sigmoid(filter)*softplus(core) ; BN2 over N rows ;
// out = softplus(atom + summed_bn)
//
// R4 design: bond rows loaded with VECTOR loads at wave-uniform addresses.
// R3 lesson: readfirstlane -> s_load chains stall on lgkmcnt (VALUBusy 27%,
// SGPR-limited pipelining). Without readfirstlane the tid-derived address is
// "divergent" to LLVM -> global_load float2s; same-addr lanes coalesce to a
// broadcast; vmcnt pipelining + 7 waves/SIMD hide the latency.
// Bond rows are 41 floats (4B-aligned): odd-lead scalar + 20 aligned float2.

#define NATOMS  100000
#define MNBR    12
#define FDIM    64
#define BDIM    41
#define C2F     128
#define BONDROW (MNBR*BDIM)   // 492
#define EPSBN   1e-5f
#define NBLK    2048          // grid for pair kernels (= #partial slots)

__device__ __forceinline__ float softplusf(float x) {
    return fmaxf(x, 0.f) + log1pf(__expf(-fabsf(x)));
}
__device__ __forceinline__ float sigmoidf(float x) {
    return 1.f / (1.f + __expf(-x));
}
__device__ __forceinline__ float bf2f(unsigned short u) {
    unsigned int v = ((unsigned int)u) << 16;
    return __builtin_bit_cast(float, v);
}
__device__ __forceinline__ unsigned short f2bf(float f) {
    unsigned int x = __builtin_bit_cast(unsigned int, f);
    unsigned int r = (x + 0x7fff + ((x >> 16) & 1)) >> 16;  // RNE
    return (unsigned short)r;
}

// ---------------- kernel 1: per-atom projections ----------------
__global__ __launch_bounds__(256) void k_project(
    const float* __restrict__ atom, const float* __restrict__ W,
    float* __restrict__ Pself, unsigned short* __restrict__ PnbrBf)
{
    __shared__ float Arow[8][64];
    const int tid  = threadIdx.x;
    const int c    = tid & 127;
    const int half = tid >> 7;           // 0 -> Pself, 1 -> Pnbr
    float w[64];
    #pragma unroll
    for (int k = 0; k < 64; ++k)
        w[k] = W[(half*64 + k)*C2F + c];

    for (int i0 = blockIdx.x*8; i0 < NATOMS; i0 += gridDim.x*8) {
        __syncthreads();
        for (int idx = tid; idx < 8*64; idx += 256) {
            int a = idx >> 6, k = idx & 63, i = i0 + a;
            Arow[a][k] = (i < NATOMS) ? atom[i*FDIM + k] : 0.f;
        }
        __syncthreads();
        #pragma unroll
        for (int a = 0; a < 8; ++a) {
            int i = i0 + a;
            if (i >= NATOMS) break;
            const float4* A4 = (const float4*)Arow[a];
            float s = 0.f;
            #pragma unroll
            for (int kk = 0; kk < 16; ++kk) {
                float4 v = A4[kk];
                s += v.x*w[4*kk] + v.y*w[4*kk+1] + v.z*w[4*kk+2] + v.w*w[4*kk+3];
            }
            if (half == 0) Pself[(size_t)i*C2F + c] = s;
            else           PnbrBf[(size_t)i*C2F + c] = f2bf(s);
        }
    }
}

// ---------------- kernel 2: BN1 batch statistics ----------------
// 1 channel/thread: f = tid&127; sub = tid>>7 (2 atoms per block-iter).
__global__ __launch_bounds__(256, 4) void k_bn1_stats(
    const int*   __restrict__ nbr,  const float* __restrict__ bond,
    const float* __restrict__ W,    const float* __restrict__ bvec,
    const float* __restrict__ Pself,const unsigned short* __restrict__ Pnbr,
    float* __restrict__ partial1)
{
    __shared__ float red[256];
    const int tid = threadIdx.x;
    const int f   = tid & 127;
    const int sub = tid >> 7;            // dynamically wave-uniform, NOT readfirstlane
    float w[BDIM];
    #pragma unroll
    for (int k = 0; k < BDIM; ++k)
        w[k] = W[(C2F + k)*C2F + f];
    const float bb = bvec[f];
    float s = 0.f, q = 0.f;

    for (int i = blockIdx.x*2 + sub; i < NATOMS; i += gridDim.x*2) {
        const float pf = Pself[(size_t)i*C2F + f] + bb;
        const float* brow0 = bond + (size_t)i*BONDROW;
        #pragma unroll 2
        for (int j = 0; j < MNBR; ++j) {
            const int r = nbr[i*MNBR + j];           // broadcast dword load
            const float pn = bf2f(Pnbr[(size_t)r*C2F + f]);
            const float* brow = brow0 + j*BDIM;
            const int lead = j & 1;                  // folds under unroll 2
            float d0 = lead ? brow[0]*w[0] : 0.f;
            float d1 = 0.f;
            const float2* b2 = (const float2*)(brow + lead);  // 8B-aligned
            #pragma unroll
            for (int t = 0; t < 10; ++t) {
                float2 va = b2[2*t], vb = b2[2*t+1];
                d0 += va.x*w[lead+4*t]   + va.y*w[lead+4*t+1];
                d1 += vb.x*w[lead+4*t+2] + vb.y*w[lead+4*t+3];
            }
            if (!lead) d0 += brow[40]*w[40];
            float g = pf + pn + d0 + d1;
            s += g; q += g*g;
        }
    }
    float* pb = partial1 + blockIdx.x*256;           // {sum[128], sumsq[128]}
    red[tid] = s; __syncthreads();
    if (tid < 128) pb[tid] = red[tid] + red[tid+128];
    __syncthreads();
    red[tid] = q; __syncthreads();
    if (tid < 128) pb[128 + tid] = red[tid] + red[tid+128];
}

// ---------------- kernel 3: finalize BN1 params ----------------
__global__ __launch_bounds__(1024) void k_bn1_finalize(
    const float* __restrict__ partial1, const float* __restrict__ scale,
    const float* __restrict__ offset,   float* __restrict__ prm1)
{
    __shared__ float redS[1024], redQ[1024];
    const int tid = threadIdx.x;
    const int c = tid & 127, h = tid >> 7;           // 8 slices
    float S = 0.f, Q = 0.f;
    for (int blk = h; blk < NBLK; blk += 8) {
        S += partial1[blk*256 + c];
        Q += partial1[blk*256 + 128 + c];
    }
    redS[tid] = S; redQ[tid] = Q;
    __syncthreads();
    if (tid < 128) {
        float Sa = 0.f, Qa = 0.f;
        #pragma unroll
        for (int hh = 0; hh < 8; ++hh) { Sa += redS[hh*128 + c]; Qa += redQ[hh*128 + c]; }
        const float invn = 1.f / (float)(NATOMS * MNBR);
        float mean = Sa * invn;
        float var  = Qa * invn - mean*mean;
        float inv  = scale[c] * rsqrtf(var + EPSBN);
        prm1[c]       = inv;
        prm1[128 + c] = offset[c] - mean*inv;        // folded offset
    }
}

// ---------------- kernel 4: main pass ----------------
// Channel pair (f, f+64) per thread; slot = tid>>6 (4 atoms per block-iter).
__global__ __launch_bounds__(256, 4) void k_main(
    const int*   __restrict__ nbr,  const float* __restrict__ bond,
    const float* __restrict__ W,    const float* __restrict__ bvec,
    const float* __restrict__ Pself,const unsigned short* __restrict__ Pnbr,
    const float* __restrict__ prm1,
    float* __restrict__ summed, float* __restrict__ partial2)
{
    __shared__ float red[256];
    const int tid  = threadIdx.x;
    const int f    = tid & 63;
    const int slot = tid >> 6;           // dynamically wave-uniform
    float wf[BDIM], wc[BDIM];
    #pragma unroll
    for (int k = 0; k < BDIM; ++k) {
        wf[k] = W[(C2F + k)*C2F + f];
        wc[k] = W[(C2F + k)*C2F + f + 64];
    }
    const float bb0 = bvec[f], bb1 = bvec[f + 64];
    const float iv0 = prm1[f],      of0 = prm1[128 + f];
    const float iv1 = prm1[f + 64], of1 = prm1[192 + f];
    float s2 = 0.f, q2 = 0.f;

    for (int i = blockIdx.x*4 + slot; i < NATOMS; i += gridDim.x*4) {
        const float pf0 = Pself[(size_t)i*C2F + f]      + bb0;
        const float pf1 = Pself[(size_t)i*C2F + f + 64] + bb1;
        const float* brow0 = bond + (size_t)i*BONDROW;
        float acc = 0.f;
        #pragma unroll 2
        for (int j = 0; j < MNBR; ++j) {
            const int r = nbr[i*MNBR + j];           // broadcast dword load
            const float pn0 = bf2f(Pnbr[(size_t)r*C2F + f]);
            const float pn1 = bf2f(Pnbr[(size_t)r*C2F + f + 64]);
            const float* brow = brow0 + j*BDIM;
            const int lead = j & 1;                  // folds under unroll 2
            float d0 = lead ? brow[0]*wf[0] : 0.f;
            float e0 = lead ? brow[0]*wc[0] : 0.f;
            float d1 = 0.f, e1 = 0.f;
            const float2* b2 = (const float2*)(brow + lead);  // 8B-aligned
            #pragma unroll
            for (int t = 0; t < 10; ++t) {
                float2 va = b2[2*t], vb = b2[2*t+1];
                d0 += va.x*wf[lead+4*t]   + va.y*wf[lead+4*t+1];
                d1 += vb.x*wf[lead+4*t+2] + vb.y*wf[lead+4*t+3];
                e0 += va.x*wc[lead+4*t]   + va.y*wc[lead+4*t+1];
                e1 += vb.x*wc[lead+4*t+2] + vb.y*wc[lead+4*t+3];
            }
            if (!lead) { d0 += brow[40]*wf[40]; e0 += brow[40]*wc[40]; }
            float g0 = pf0 + pn0 + d0 + d1;
            float g1 = pf1 + pn1 + e0 + e1;
            float y0 = g0*iv0 + of0;                 // BN1 filter (folded)
            float y1 = g1*iv1 + of1;                 // BN1 core
            acc += sigmoidf(y0) * softplusf(y1);
        }
        summed[(size_t)i*FDIM + f] = acc;
        s2 += acc; q2 += acc*acc;
    }
    float* pb = partial2 + blockIdx.x*128;           // {sum[64], sumsq[64]}
    red[tid] = s2; __syncthreads();
    if (tid < 64) pb[tid]      = red[tid] + red[tid+64] + red[tid+128] + red[tid+192];
    __syncthreads();
    red[tid] = q2; __syncthreads();
    if (tid < 64) pb[64 + tid] = red[tid] + red[tid+64] + red[tid+128] + red[tid+192];
}

// ---------------- kernel 5: finalize BN2 params ----------------
__global__ __launch_bounds__(1024) void k_bn2_finalize(
    const float* __restrict__ partial2, const float* __restrict__ scale,
    const float* __restrict__ offset,   float* __restrict__ prm2)
{
    __shared__ float redS[1024], redQ[1024];
    const int tid = threadIdx.x;
    const int f = tid & 63, h = tid >> 6;            // 16 slices
    float S = 0.f, Q = 0.f;
    for (int blk = h; blk < NBLK; blk += 16) {
        S += partial2[blk*128 + f];
        Q += partial2[blk*128 + 64 + f];
    }
    redS[tid] = S; redQ[tid] = Q;
    __syncthreads();
    if (tid < 64) {
        float Sa = 0.f, Qa = 0.f;
        #pragma unroll
        for (int hh = 0; hh < 16; ++hh) { Sa += redS[hh*64 + f]; Qa += redQ[hh*64 + f]; }
        const float invn = 1.f / (float)NATOMS;
        float mean = Sa * invn;
        float var  = Qa * invn - mean*mean;
        float inv  = scale[f] * rsqrtf(var + EPSBN);
        prm2[f]      = inv;
        prm2[64 + f] = offset[f] - mean*inv;
    }
}

// ---------------- kernel 6: residual + softplus ----------------
__global__ __launch_bounds__(256) void k_final(
    const float* __restrict__ atom, const float* __restrict__ summed,
    const float* __restrict__ prm2, float* __restrict__ out)
{
    __shared__ float iv[64], of[64];
    if (threadIdx.x < 64) {
        iv[threadIdx.x] = prm2[threadIdx.x];
        of[threadIdx.x] = prm2[64 + threadIdx.x];
    }
    __syncthreads();
    const int total4 = NATOMS*FDIM/4;
    for (int t = blockIdx.x*blockDim.x + threadIdx.x; t < total4;
         t += gridDim.x*blockDim.x) {
        float4 a = ((const float4*)atom)[t];
        float4 s = ((const float4*)summed)[t];
        int fb = (t*4) & 63;
        float4 r;
        r.x = softplusf(a.x + s.x*iv[fb]   + of[fb]);
        r.y = softplusf(a.y + s.y*iv[fb+1] + of[fb+1]);
        r.z = softplusf(a.z + s.z*iv[fb+2] + of[fb+2]);
        r.w = softplusf(a.w + s.w*iv[fb+3] + of[fb+3]);
        ((float4*)out)[t] = r;
    }
}

extern "C" void kernel_launch(void* const* d_in, const int* in_sizes, int n_in,
                              void* d_out, int out_size, void* d_ws, size_t ws_size,
                              hipStream_t stream)
{
    const int*   nbr  = (const int*)  d_in[0];
    const float* atom = (const float*)d_in[1];
    const float* bond = (const float*)d_in[2];
    const float* W    = (const float*)d_in[3];
    const float* bvec = (const float*)d_in[4];
    const float* s1   = (const float*)d_in[5];
    const float* o1   = (const float*)d_in[6];
    const float* s2   = (const float*)d_in[7];
    const float* o2   = (const float*)d_in[8];
    float* out = (float*)d_out;

    float*          Pself  = (float*)d_ws;                              // N*128 f32
    unsigned short* PnbrBf = (unsigned short*)(Pself + (size_t)NATOMS*C2F); // N*128 bf16
    float*          summed = (float*)(PnbrBf + (size_t)NATOMS*C2F);     // N*64 f32
    float* partial1 = summed   + (size_t)NATOMS*FDIM;                   // NBLK*256
    float* partial2 = partial1 + (size_t)NBLK*256;                      // NBLK*128
    float* prm1     = partial2 + (size_t)NBLK*128;                      // 256
    float* prm2     = prm1     + 256;                                   // 128

    hipLaunchKernelGGL(k_project,      dim3(1024), dim3(256),  0, stream,
                       atom, W, Pself, PnbrBf);
    hipLaunchKernelGGL(k_bn1_stats,    dim3(NBLK), dim3(256),  0, stream,
                       nbr, bond, W, bvec, Pself, PnbrBf, partial1);
    hipLaunchKernelGGL(k_bn1_finalize, dim3(1),    dim3(1024), 0, stream,
                       partial1, s1, o1, prm1);
    hipLaunchKernelGGL(k_main,         dim3(NBLK), dim3(256),  0, stream,
                       nbr, bond, W, bvec, Pself, PnbrBf, prm1, summed, partial2);
    hipLaunchKernelGGL(k_bn2_finalize, dim3(1),    dim3(1024), 0, stream,
                       partial2, s2, o2, prm2);
    hipLaunchKernelGGL(k_final,        dim3(2048), dim3(256),  0, stream,
                       atom, summed, prm2, out);
}

// Round 5
// 539.964 us; speedup vs baseline: 7.5298x; 7.5298x over previous
//
#include <hip/hip_runtime.h>
#include <math.h>

// CGConv: N=100000 atoms, M=12 nbrs, F=64 atom-feat, B=41 bond-feat
// gated = [self | nbr | bond] @ W + b ; BN1 over N*M rows ;
// summed = sum_j sigmoid(filter)*softplus(core) ; BN2 over N rows ;
// out = softplus(atom + summed_bn)
//
// R5 design: MFMA. Per 4-atom group: 48 pairs (M=48 -> 3 m-tiles of 16),
// K = 169 padded to 192 (6 k-steps of 32), N = 128 channels (8 n-tiles).
// A rows [self|nbr|bond] staged bf16 in LDS; W prepacked bf16 into B-frag
// layout (weights = 48 VGPR/wave, NOT 82/thread regs -- kills the spill
// disease of R2/R4). Wave w owns n-tiles {w, w+4} so filter ch f and core
// ch f+64 land in the SAME lane -> gate in-register.
// k-layout note: any k-permutation sigma(lanegroup,e) cancels if A and B
// packs share it; only C/D layout matters (HW-verified m89:
// col=lane&15, row=(lane>>4)*4+reg).
// b provably cancels through BN1 (shift-invariance) -> ignored.

#define NATOMS  100000
#define MNBR    12
#define FDIM    64
#define BDIM    41
#define KDIM    (2*FDIM + BDIM)   // 169
#define KSTEPS  6                 // K padded to 192
#define C2F     128
#define EPSBN   1e-5f
#define NBLK    2048              // grid for pair kernels (= #partial slots)
#define GROUPS  (NATOMS/4)        // 25000 groups of 4 atoms (48 pairs)
#define AROW    200               // A-tile LDS row stride (shorts): 192 + 8 pad

typedef __attribute__((ext_vector_type(8))) short  short8;   // bf16 x8 frag
typedef __attribute__((ext_vector_type(4))) float  f32x4;    // C/D frag

__device__ __forceinline__ float softplusf(float x) {
    return fmaxf(x, 0.f) + log1pf(__expf(-fabsf(x)));
}
__device__ __forceinline__ float sigmoidf(float x) {
    return 1.f / (1.f + __expf(-x));
}
__device__ __forceinline__ unsigned short f2bf(float f) {
    unsigned int x = __builtin_bit_cast(unsigned int, f);
    unsigned int r = (x + 0x7fff + ((x >> 16) & 1)) >> 16;   // RNE
    return (unsigned short)r;
}
__device__ __forceinline__ uint2 pk4(float a, float b, float c, float d) {
    uint2 r;
    r.x = (unsigned)f2bf(a) | ((unsigned)f2bf(b) << 16);
    r.y = (unsigned)f2bf(c) | ((unsigned)f2bf(d) << 16);
    return r;
}

// ---------------- kernel 0: prepack W into B-fragment layout ----------------
// Wpk[n][ks][lane][e] = bf16( W[k][col] ), k = ks*32 + (lane>>4)*8 + e (sigma),
// col = n*16 + (lane&15); zero-padded for k >= 169.
__global__ __launch_bounds__(256) void k_pack_w(
    const float* __restrict__ W, unsigned short* __restrict__ Wpk)
{
    for (int idx = blockIdx.x*256 + threadIdx.x; idx < 8*KSTEPS*64*8;
         idx += gridDim.x*256) {
        int e    = idx & 7;
        int lane = (idx >> 3) & 63;
        int ks   = (idx >> 9) % KSTEPS;
        int n    = idx / (KSTEPS*512);
        int k    = ks*32 + (lane >> 4)*8 + e;
        int col  = n*16 + (lane & 15);
        float v  = (k < KDIM) ? W[k*C2F + col] : 0.f;
        Wpk[idx] = f2bf(v);
    }
}

// ---------------- kernel 1: BN1 batch statistics (MFMA) ----------------
__global__ __launch_bounds__(256, 3) void k_stats(
    const int* __restrict__ nbr, const float* __restrict__ atomF,
    const float* __restrict__ bond, const unsigned short* __restrict__ Wpk,
    float* __restrict__ partial1)
{
    __shared__ __align__(16) unsigned short A[48*AROW];
    __shared__ int   Ni[48];
    __shared__ float red[256];
    const int tid  = threadIdx.x;
    const int w    = tid >> 6;        // wave 0..3 -> n-tiles {w, w+4}
    const int lane = tid & 63;
    const int g    = lane >> 4;
    const int x    = lane & 15;

    short8 Bf0[KSTEPS], Bf1[KSTEPS];  // resident B frags (48 VGPR)
    #pragma unroll
    for (int ks = 0; ks < KSTEPS; ++ks) {
        Bf0[ks] = *(const short8*)(Wpk + ((w    *KSTEPS + ks)*64 + lane)*8);
        Bf1[ks] = *(const short8*)(Wpk + (((w+4)*KSTEPS + ks)*64 + lane)*8);
    }
    float s0 = 0.f, s1 = 0.f, q0 = 0.f, q1 = 0.f;

    for (int grp = blockIdx.x; grp < GROUPS; grp += gridDim.x) {
        const int base = grp*4;
        __syncthreads();                          // protect A from prior reads
        if (tid < 48) Ni[tid] = nbr[base*MNBR + tid];
        __syncthreads();
        #pragma unroll
        for (int it = 0; it < 3; ++it) {          // stage A: 768 slots (p, c)
            int idx = it*256 + tid;
            int p = idx >> 4, c = idx & 15;
            int i = base + p/12;
            int r = Ni[p];
            f32x4 vs = *(const f32x4*)(atomF + (size_t)i*FDIM + 4*c);
            f32x4 vn = *(const f32x4*)(atomF + (size_t)r*FDIM + 4*c);
            const float* bp = bond + (size_t)i*(MNBR*BDIM) + (p%12)*BDIM;
            int e0 = 4*c;
            float b0 = (e0+0 < BDIM) ? bp[e0+0] : 0.f;
            float b1 = (e0+1 < BDIM) ? bp[e0+1] : 0.f;
            float b2 = (e0+2 < BDIM) ? bp[e0+2] : 0.f;
            float b3 = (e0+3 < BDIM) ? bp[e0+3] : 0.f;
            unsigned short* Ar = A + p*AROW;
            *(uint2*)(Ar +        4*c) = pk4(vs.x, vs.y, vs.z, vs.w);
            *(uint2*)(Ar +  64  + 4*c) = pk4(vn.x, vn.y, vn.z, vn.w);
            *(uint2*)(Ar + 128  + 4*c) = pk4(b0, b1, b2, b3);
        }
        __syncthreads();
        f32x4 z = {0.f, 0.f, 0.f, 0.f};
        f32x4 acc[3][2];
        #pragma unroll
        for (int m = 0; m < 3; ++m) { acc[m][0] = z; acc[m][1] = z; }
        #pragma unroll
        for (int ks = 0; ks < KSTEPS; ++ks) {
            #pragma unroll
            for (int m = 0; m < 3; ++m) {
                short8 a = *(const short8*)(A + (m*16 + x)*AROW + ks*32 + g*8);
                acc[m][0] = __builtin_amdgcn_mfma_f32_16x16x32_bf16(a, Bf0[ks], acc[m][0], 0, 0, 0);
                acc[m][1] = __builtin_amdgcn_mfma_f32_16x16x32_bf16(a, Bf1[ks], acc[m][1], 0, 0, 0);
            }
        }
        #pragma unroll
        for (int m = 0; m < 3; ++m) {
            #pragma unroll
            for (int rg = 0; rg < 4; ++rg) {
                float v0 = acc[m][0][rg], v1 = acc[m][1][rg];
                s0 += v0; q0 += v0*v0;
                s1 += v1; q1 += v1*v1;
            }
        }
    }
    // block reduce: channel ch0 = w*16+x (from n-tile w), ch1 = ch0+64
    float* pb = partial1 + blockIdx.x*256;        // {sum[128], sumsq[128]}
    red[tid] = s0; __syncthreads();
    if (lane < 16) pb[w*16 + x]       = red[w*64+x] + red[w*64+16+x] + red[w*64+32+x] + red[w*64+48+x];
    __syncthreads();
    red[tid] = s1; __syncthreads();
    if (lane < 16) pb[64 + w*16 + x]  = red[w*64+x] + red[w*64+16+x] + red[w*64+32+x] + red[w*64+48+x];
    __syncthreads();
    red[tid] = q0; __syncthreads();
    if (lane < 16) pb[128 + w*16 + x] = red[w*64+x] + red[w*64+16+x] + red[w*64+32+x] + red[w*64+48+x];
    __syncthreads();
    red[tid] = q1; __syncthreads();
    if (lane < 16) pb[192 + w*16 + x] = red[w*64+x] + red[w*64+16+x] + red[w*64+32+x] + red[w*64+48+x];
}

// ---------------- kernel 2: finalize BN1 params ----------------
__global__ __launch_bounds__(1024) void k_bn1_finalize(
    const float* __restrict__ partial1, const float* __restrict__ scale,
    const float* __restrict__ offset,   float* __restrict__ prm1)
{
    __shared__ float redS[1024], redQ[1024];
    const int tid = threadIdx.x;
    const int c = tid & 127, h = tid >> 7;        // 8 slices
    float S = 0.f, Q = 0.f;
    for (int blk = h; blk < NBLK; blk += 8) {
        S += partial1[blk*256 + c];
        Q += partial1[blk*256 + 128 + c];
    }
    redS[tid] = S; redQ[tid] = Q;
    __syncthreads();
    if (tid < 128) {
        float Sa = 0.f, Qa = 0.f;
        #pragma unroll
        for (int hh = 0; hh < 8; ++hh) { Sa += redS[hh*128 + c]; Qa += redQ[hh*128 + c]; }
        const float invn = 1.f / (float)(NATOMS * MNBR);
        float mean = Sa * invn;                   // mean of g_mfma (b cancels)
        float var  = Qa * invn - mean*mean;
        float inv  = scale[c] * rsqrtf(var + EPSBN);
        prm1[c]       = inv;
        prm1[128 + c] = offset[c] - mean*inv;     // folded offset
    }
}

// ---------------- kernel 3: main pass (MFMA + gate + nbr-sum) ----------------
__global__ __launch_bounds__(256, 3) void k_mainm(
    const int* __restrict__ nbr, const float* __restrict__ atomF,
    const float* __restrict__ bond, const unsigned short* __restrict__ Wpk,
    const float* __restrict__ prm1,
    float* __restrict__ summed, float* __restrict__ partial2)
{
    __shared__ __align__(16) unsigned short A[48*AROW];
    __shared__ float Y[48*68];                    // gate values [pair][f], padded
    __shared__ int   Ni[48];
    __shared__ float red[256];
    const int tid  = threadIdx.x;
    const int w    = tid >> 6;
    const int lane = tid & 63;
    const int g    = lane >> 4;
    const int x    = lane & 15;

    short8 Bf0[KSTEPS], Bf1[KSTEPS];
    #pragma unroll
    for (int ks = 0; ks < KSTEPS; ++ks) {
        Bf0[ks] = *(const short8*)(Wpk + ((w    *KSTEPS + ks)*64 + lane)*8);
        Bf1[ks] = *(const short8*)(Wpk + (((w+4)*KSTEPS + ks)*64 + lane)*8);
    }
    const int ch0 = w*16 + x;                     // filter channel (0..63)
    const float iv0 = prm1[ch0],      of0 = prm1[128 + ch0];
    const float iv1 = prm1[ch0 + 64], of1 = prm1[192 + ch0];
    float s2 = 0.f, q2 = 0.f;

    for (int grp = blockIdx.x; grp < GROUPS; grp += gridDim.x) {
        const int base = grp*4;
        __syncthreads();                          // protect A and Y
        if (tid < 48) Ni[tid] = nbr[base*MNBR + tid];
        __syncthreads();
        #pragma unroll
        for (int it = 0; it < 3; ++it) {
            int idx = it*256 + tid;
            int p = idx >> 4, c = idx & 15;
            int i = base + p/12;
            int r = Ni[p];
            f32x4 vs = *(const f32x4*)(atomF + (size_t)i*FDIM + 4*c);
            f32x4 vn = *(const f32x4*)(atomF + (size_t)r*FDIM + 4*c);
            const float* bp = bond + (size_t)i*(MNBR*BDIM) + (p%12)*BDIM;
            int e0 = 4*c;
            float b0 = (e0+0 < BDIM) ? bp[e0+0] : 0.f;
            float b1 = (e0+1 < BDIM) ? bp[e0+1] : 0.f;
            float b2 = (e0+2 < BDIM) ? bp[e0+2] : 0.f;
            float b3 = (e0+3 < BDIM) ? bp[e0+3] : 0.f;
            unsigned short* Ar = A + p*AROW;
            *(uint2*)(Ar +       4*c) = pk4(vs.x, vs.y, vs.z, vs.w);
            *(uint2*)(Ar + 64  + 4*c) = pk4(vn.x, vn.y, vn.z, vn.w);
            *(uint2*)(Ar + 128 + 4*c) = pk4(b0, b1, b2, b3);
        }
        __syncthreads();
        f32x4 z = {0.f, 0.f, 0.f, 0.f};
        f32x4 acc[3][2];
        #pragma unroll
        for (int m = 0; m < 3; ++m) { acc[m][0] = z; acc[m][1] = z; }
        #pragma unroll
        for (int ks = 0; ks < KSTEPS; ++ks) {
            #pragma unroll
            for (int m = 0; m < 3; ++m) {
                short8 a = *(const short8*)(A + (m*16 + x)*AROW + ks*32 + g*8);
                acc[m][0] = __builtin_amdgcn_mfma_f32_16x16x32_bf16(a, Bf0[ks], acc[m][0], 0, 0, 0);
                acc[m][1] = __builtin_amdgcn_mfma_f32_16x16x32_bf16(a, Bf1[ks], acc[m][1], 0, 0, 0);
            }
        }
        // BN1 + gate, in-register (filter & core in same lane), -> Y
        #pragma unroll
        for (int m = 0; m < 3; ++m) {
            #pragma unroll
            for (int rg = 0; rg < 4; ++rg) {
                float y0 = acc[m][0][rg]*iv0 + of0;
                float y1 = acc[m][1][rg]*iv1 + of1;
                Y[(m*16 + g*4 + rg)*68 + ch0] = sigmoidf(y0) * softplusf(y1);
            }
        }
        __syncthreads();
        // neighbor-sum: wave w owns atom-slot w, lane = channel f
        float accf = 0.f;
        #pragma unroll
        for (int j = 0; j < MNBR; ++j)
            accf += Y[(w*MNBR + j)*68 + lane];
        summed[(size_t)(base + w)*FDIM + lane] = accf;
        s2 += accf; q2 += accf*accf;
    }
    float* pb = partial2 + blockIdx.x*128;        // {sum[64], sumsq[64]}
    red[tid] = s2; __syncthreads();
    if (tid < 64) pb[tid]      = red[tid] + red[tid+64] + red[tid+128] + red[tid+192];
    __syncthreads();
    red[tid] = q2; __syncthreads();
    if (tid < 64) pb[64 + tid] = red[tid] + red[tid+64] + red[tid+128] + red[tid+192];
}

// ---------------- kernel 4: finalize BN2 params ----------------
__global__ __launch_bounds__(1024) void k_bn2_finalize(
    const float* __restrict__ partial2, const float* __restrict__ scale,
    const float* __restrict__ offset,   float* __restrict__ prm2)
{
    __shared__ float redS[1024], redQ[1024];
    const int tid = threadIdx.x;
    const int f = tid & 63, h = tid >> 6;         // 16 slices
    float S = 0.f, Q = 0.f;
    for (int blk = h; blk < NBLK; blk += 16) {
        S += partial2[blk*128 + f];
        Q += partial2[blk*128 + 64 + f];
    }
    redS[tid] = S; redQ[tid] = Q;
    __syncthreads();
    if (tid < 64) {
        float Sa = 0.f, Qa = 0.f;
        #pragma unroll
        for (int hh = 0; hh < 16; ++hh) { Sa += redS[hh*64 + f]; Qa += redQ[hh*64 + f]; }
        const float invn = 1.f / (float)NATOMS;
        float mean = Sa * invn;
        float var  = Qa * invn - mean*mean;
        float inv  = scale[f] * rsqrtf(var + EPSBN);
        prm2[f]      = inv;
        prm2[64 + f] = offset[f] - mean*inv;
    }
}

// ---------------- kernel 5: residual + softplus ----------------
__global__ __launch_bounds__(256) void k_final(
    const float* __restrict__ atomF, const float* __restrict__ summed,
    const float* __restrict__ prm2, float* __restrict__ out)
{
    __shared__ float iv[64], of[64];
    if (threadIdx.x < 64) {
        iv[threadIdx.x] = prm2[threadIdx.x];
        of[threadIdx.x] = prm2[64 + threadIdx.x];
    }
    __syncthreads();
    const int total4 = NATOMS*FDIM/4;
    for (int t = blockIdx.x*blockDim.x + threadIdx.x; t < total4;
         t += gridDim.x*blockDim.x) {
        float4 a = ((const float4*)atomF)[t];
        float4 s = ((const float4*)summed)[t];
        int fb = (t*4) & 63;
        float4 r;
        r.x = softplusf(a.x + s.x*iv[fb]   + of[fb]);
        r.y = softplusf(a.y + s.y*iv[fb+1] + of[fb+1]);
        r.z = softplusf(a.z + s.z*iv[fb+2] + of[fb+2]);
        r.w = softplusf(a.w + s.w*iv[fb+3] + of[fb+3]);
        ((float4*)out)[t] = r;
    }
}

extern "C" void kernel_launch(void* const* d_in, const int* in_sizes, int n_in,
                              void* d_out, int out_size, void* d_ws, size_t ws_size,
                              hipStream_t stream)
{
    const int*   nbr   = (const int*)  d_in[0];
    const float* atomF = (const float*)d_in[1];
    const float* bond  = (const float*)d_in[2];
    const float* W     = (const float*)d_in[3];
    // d_in[4] = b: provably cancels through BN1 (shift-invariance) -> unused
    const float* s1    = (const float*)d_in[5];
    const float* o1    = (const float*)d_in[6];
    const float* s2    = (const float*)d_in[7];
    const float* o2    = (const float*)d_in[8];
    float* out = (float*)d_out;

    unsigned short* Wpk = (unsigned short*)d_ws;                 // 8*6*64*8 = 24576 bf16
    float* summed   = (float*)(Wpk + 24576);                     // N*64 f32
    float* partial1 = summed   + (size_t)NATOMS*FDIM;            // NBLK*256
    float* partial2 = partial1 + (size_t)NBLK*256;               // NBLK*128
    float* prm1     = partial2 + (size_t)NBLK*128;               // 256
    float* prm2     = prm1     + 256;                            // 128

    hipLaunchKernelGGL(k_pack_w,       dim3(96),   dim3(256),  0, stream, W, Wpk);
    hipLaunchKernelGGL(k_stats,        dim3(NBLK), dim3(256),  0, stream,
                       nbr, atomF, bond, Wpk, partial1);
    hipLaunchKernelGGL(k_bn1_finalize, dim3(1),    dim3(1024), 0, stream,
                       partial1, s1, o1, prm1);
    hipLaunchKernelGGL(k_mainm,        dim3(NBLK), dim3(256),  0, stream,
                       nbr, atomF, bond, Wpk, prm1, summed, partial2);
    hipLaunchKernelGGL(k_bn2_finalize, dim3(1),    dim3(1024), 0, stream,
                       partial2, s2, o2, prm2);
    hipLaunchKernelGGL(k_final,        dim3(2048), dim3(256),  0, stream,
                       atomF, summed, prm2, out);
}

// Round 6
// 475.222 us; speedup vs baseline: 8.5556x; 1.1362x over previous
//
#include <hip/hip_runtime.h>
#include <hip/hip_bf16.h>
#include <math.h>

// CGConv: N=100000 atoms, M=12 nbrs, F=64 atom-feat, B=41 bond-feat
// gated = [self | nbr | bond] @ W + b ; BN1 over N*M rows ;
// summed = sum_j sigmoid(filter)*softplus(core) ; BN2 over N rows ;
// out = softplus(atom + summed_bn)
//
// R6: self-projection hoisted out of the pair MFMA.
//  - Pself = atom @ W_self precomputed by MFMA kernel k_proj (f32, N x 128).
//  - Pair kernels: A rows = [nbr(64) | bond(41) | pad] K=128 (4 ksteps),
//    M = 48 pairs (4 atoms), N = 128 channels. Wave w owns n-tiles {w, w+4}
//    so filter ch f and core ch f+64 are in the SAME lane.
//  - Pself added in f32 epilogue (atom index provably uniform per (m,g):
//    (m*16+g*4)%12 <= 8, so the 4 rg rows never cross an atom boundary).
//  - bf16 pack via __float2bfloat16 casts (compiler emits v_cvt_pk_bf16_f32),
//    not hand bit-ops (R5 lesson: 9216 bit-op conversions/group = VALU 98%).
//  - A-row stride 136 shorts: dword-stride 68 == 4 mod 32 -> even bank load.
//  - bias b cancels through BN1 (shift invariance) -> ignored.

#define NATOMS  100000
#define MNBR    12
#define FDIM    64
#define BDIM    41
#define C2F     128
#define EPSBN   1e-5f
#define NBLK    2048              // pair-kernel grid (= #partial slots)
#define GROUPS  (NATOMS/4)        // 25000 groups of 4 atoms = 48 pairs
#define AR      136               // pair A-tile row stride (shorts)
#define PR      72                // proj A-tile row stride (shorts)

typedef __attribute__((ext_vector_type(8))) short  short8;   // bf16 x8 frag
typedef __attribute__((ext_vector_type(4))) float  f32x4;    // C/D frag

__device__ __forceinline__ float softplusf(float x) {
    return fmaxf(x, 0.f) + __logf(1.f + __expf(-fabsf(x)));
}
__device__ __forceinline__ float sigmoidf(float x) {
    return 1.f / (1.f + __expf(-x));
}
__device__ __forceinline__ unsigned short f2bf(float f) {   // pack kernel only
    unsigned int x = __builtin_bit_cast(unsigned int, f);
    unsigned int r = (x + 0x7fff + ((x >> 16) & 1)) >> 16;  // RNE
    return (unsigned short)r;
}
__device__ __forceinline__ unsigned int pkbf(float a, float b) {
    unsigned short lo = __builtin_bit_cast(unsigned short, __float2bfloat16(a));
    unsigned short hi = __builtin_bit_cast(unsigned short, __float2bfloat16(b));
    return (unsigned)lo | ((unsigned)hi << 16);
}

// ---------------- kernel 0: prepack W fragments ----------------
// Wsn: self block, [n<8][ks<2][lane][e], k = ks*32+(lane>>4)*8+e, col=n*16+(lane&15)
// Wpk: nbr+bond block, [n<8][ks<4][lane][e]; k<105 -> W[(64+k)][col] else 0
__global__ __launch_bounds__(256) void k_pack(
    const float* __restrict__ W,
    unsigned short* __restrict__ Wsn, unsigned short* __restrict__ Wpk)
{
    const int t0 = blockIdx.x*256 + threadIdx.x;
    for (int idx = t0; idx < 8*2*64*8; idx += gridDim.x*256) {
        int e = idx & 7, lane = (idx >> 3) & 63, ks = (idx >> 9) & 1, n = idx >> 10;
        int k   = ks*32 + (lane >> 4)*8 + e;
        int col = n*16 + (lane & 15);
        Wsn[idx] = f2bf(W[k*C2F + col]);
    }
    for (int idx = t0; idx < 8*4*64*8; idx += gridDim.x*256) {
        int e = idx & 7, lane = (idx >> 3) & 63, ks = (idx >> 9) & 3, n = idx >> 11;
        int k   = ks*32 + (lane >> 4)*8 + e;
        int col = n*16 + (lane & 15);
        float v = (k < 105) ? W[(64 + k)*C2F + col] : 0.f;
        Wpk[idx] = f2bf(v);
    }
}

// ---------------- kernel 1: Pself = atom @ W_self (MFMA) ----------------
__global__ __launch_bounds__(256, 4) void k_proj(
    const float* __restrict__ atomF, const unsigned short* __restrict__ Wsn,
    float* __restrict__ Pself)
{
    __shared__ __align__(16) unsigned short A[64*PR];
    const int tid = threadIdx.x, w = tid >> 6, lane = tid & 63;
    const int g = lane >> 4, x = lane & 15;
    short8 B0[2], B1[2];
    #pragma unroll
    for (int ks = 0; ks < 2; ++ks) {
        B0[ks] = *(const short8*)(Wsn + ((w*2 + ks)*64 + lane)*8);
        B1[ks] = *(const short8*)(Wsn + (((w+4)*2 + ks)*64 + lane)*8);
    }
    for (int a0 = blockIdx.x*64; a0 < NATOMS; a0 += gridDim.x*64) {
        __syncthreads();
        #pragma unroll
        for (int it = 0; it < 4; ++it) {
            int idx = it*256 + tid;
            int p = idx >> 4, c = idx & 15;
            int i = a0 + p;
            float4 v = make_float4(0.f, 0.f, 0.f, 0.f);
            if (i < NATOMS) v = *(const float4*)(atomF + (size_t)i*FDIM + 4*c);
            uint2 u; u.x = pkbf(v.x, v.y); u.y = pkbf(v.z, v.w);
            *(uint2*)(A + p*PR + 4*c) = u;
        }
        __syncthreads();
        f32x4 z = {0.f, 0.f, 0.f, 0.f};
        f32x4 acc[4][2];
        #pragma unroll
        for (int m = 0; m < 4; ++m) { acc[m][0] = z; acc[m][1] = z; }
        #pragma unroll
        for (int ks = 0; ks < 2; ++ks) {
            #pragma unroll
            for (int m = 0; m < 4; ++m) {
                short8 a = *(const short8*)(A + (m*16 + x)*PR + ks*32 + g*8);
                acc[m][0] = __builtin_amdgcn_mfma_f32_16x16x32_bf16(a, B0[ks], acc[m][0], 0, 0, 0);
                acc[m][1] = __builtin_amdgcn_mfma_f32_16x16x32_bf16(a, B1[ks], acc[m][1], 0, 0, 0);
            }
        }
        #pragma unroll
        for (int m = 0; m < 4; ++m) {
            int i = a0 + m*16 + g*4;
            #pragma unroll
            for (int rg = 0; rg < 4; ++rg) {
                if (i + rg < NATOMS) {
                    Pself[(size_t)(i+rg)*C2F + w*16 + x]       = acc[m][0][rg];
                    Pself[(size_t)(i+rg)*C2F + (w+4)*16 + x]   = acc[m][1][rg];
                }
            }
        }
    }
}

// ---------------- shared pair-tile machinery ----------------
// Stage A: 1536 slots (48 pairs x 32), p=idx>>5, c=idx&31:
//   c<16  : nbr row quad  (aligned float4 from atomF[r])
//   16<=c<27: bond quad cc=c-16 (4 scalar loads, row is 41 floats)
//   rest  : pad, pre-zeroed once

// ---------------- kernel 2: BN1 batch statistics ----------------
__global__ __launch_bounds__(256, 4) void k_stats(
    const int* __restrict__ nbr, const float* __restrict__ atomF,
    const float* __restrict__ bond, const unsigned short* __restrict__ Wpk,
    const float* __restrict__ Pself, float* __restrict__ partial1)
{
    __shared__ __align__(16) unsigned short A[48*AR];
    __shared__ int Ni[48];
    const int tid = threadIdx.x, w = tid >> 6, lane = tid & 63;
    const int g = lane >> 4, x = lane & 15;
    const int ch0 = w*16 + x;
    short8 B0[4], B1[4];
    #pragma unroll
    for (int ks = 0; ks < 4; ++ks) {
        B0[ks] = *(const short8*)(Wpk + ((w*4 + ks)*64 + lane)*8);
        B1[ks] = *(const short8*)(Wpk + (((w+4)*4 + ks)*64 + lane)*8);
    }
    for (int idx = tid; idx < 48*AR/2; idx += 256) ((unsigned int*)A)[idx] = 0u;
    float s0 = 0.f, q0 = 0.f, s1 = 0.f, q1 = 0.f;

    for (int grp = blockIdx.x; grp < GROUPS; grp += gridDim.x) {
        const int base = grp*4;
        __syncthreads();
        if (tid < 48) Ni[tid] = nbr[base*MNBR + tid];
        __syncthreads();
        #pragma unroll
        for (int it = 0; it < 6; ++it) {
            int idx = it*256 + tid;
            int p = idx >> 5, c = idx & 31;
            if (c < 16) {
                int r = Ni[p];
                float4 v = *(const float4*)(atomF + (size_t)r*FDIM + 4*c);
                uint2 u; u.x = pkbf(v.x, v.y); u.y = pkbf(v.z, v.w);
                *(uint2*)(A + p*AR + 4*c) = u;
            } else if (c < 27) {
                int cc = c - 16;
                int pa = p/12;
                const float* bp = bond + (size_t)(base + pa)*(MNBR*BDIM)
                                       + (p - pa*12)*BDIM + 4*cc;
                float b0 = bp[0], b1 = 0.f, b2 = 0.f, b3 = 0.f;
                if (cc < 10) { b1 = bp[1]; b2 = bp[2]; b3 = bp[3]; }
                uint2 u; u.x = pkbf(b0, b1); u.y = pkbf(b2, b3);
                *(uint2*)(A + p*AR + 64 + 4*cc) = u;
            }
        }
        __syncthreads();
        f32x4 z = {0.f, 0.f, 0.f, 0.f};
        f32x4 acc[3][2];
        #pragma unroll
        for (int m = 0; m < 3; ++m) { acc[m][0] = z; acc[m][1] = z; }
        #pragma unroll
        for (int ks = 0; ks < 4; ++ks) {
            #pragma unroll
            for (int m = 0; m < 3; ++m) {
                short8 a = *(const short8*)(A + (m*16 + x)*AR + ks*32 + g*8);
                acc[m][0] = __builtin_amdgcn_mfma_f32_16x16x32_bf16(a, B0[ks], acc[m][0], 0, 0, 0);
                acc[m][1] = __builtin_amdgcn_mfma_f32_16x16x32_bf16(a, B1[ks], acc[m][1], 0, 0, 0);
            }
        }
        #pragma unroll
        for (int m = 0; m < 3; ++m) {
            int ia = base + (m*16 + g*4)/12;       // uniform over rg (proven)
            float ps0 = Pself[(size_t)ia*C2F + ch0];
            float ps1 = Pself[(size_t)ia*C2F + 64 + ch0];
            #pragma unroll
            for (int rg = 0; rg < 4; ++rg) {
                float v0 = acc[m][0][rg] + ps0;
                float v1 = acc[m][1][rg] + ps1;
                s0 += v0; q0 = fmaf(v0, v0, q0);
                s1 += v1; q1 = fmaf(v1, v1, q1);
            }
        }
    }
    s0 += __shfl_xor(s0, 16); s0 += __shfl_xor(s0, 32);
    s1 += __shfl_xor(s1, 16); s1 += __shfl_xor(s1, 32);
    q0 += __shfl_xor(q0, 16); q0 += __shfl_xor(q0, 32);
    q1 += __shfl_xor(q1, 16); q1 += __shfl_xor(q1, 32);
    if (g == 0) {
        float* pb = partial1 + blockIdx.x*256;     // {sum[128], sumsq[128]}
        pb[ch0]            = s0; pb[64 + ch0]        = s1;
        pb[C2F + ch0]      = q0; pb[C2F + 64 + ch0]  = q1;
    }
}

// ---------------- kernel: partial reduce 2048 -> 128 slots ----------------
__global__ __launch_bounds__(256) void k_red(
    const float* __restrict__ in, float* __restrict__ outp, int width)
{
    const int b = blockIdx.x;                       // 128 blocks x 16 slots
    for (int c = threadIdx.x; c < width; c += 256) {
        float s = 0.f;
        #pragma unroll 4
        for (int k = 0; k < 16; ++k) s += in[(size_t)(b*16 + k)*width + c];
        outp[(size_t)b*width + c] = s;
    }
}

// ---------------- kernel 3: finalize BN1 params ----------------
__global__ __launch_bounds__(1024) void k_bn1_finalize(
    const float* __restrict__ red1, const float* __restrict__ scale,
    const float* __restrict__ offset, float* __restrict__ prm1)
{
    __shared__ float redS[1024], redQ[1024];
    const int tid = threadIdx.x, c = tid & 127, h = tid >> 7;   // 8 slices
    float S = 0.f, Q = 0.f;
    for (int blk = h; blk < 128; blk += 8) {
        S += red1[blk*256 + c];
        Q += red1[blk*256 + 128 + c];
    }
    redS[tid] = S; redQ[tid] = Q;
    __syncthreads();
    if (tid < 128) {
        float Sa = 0.f, Qa = 0.f;
        #pragma unroll
        for (int hh = 0; hh < 8; ++hh) { Sa += redS[hh*128 + c]; Qa += redQ[hh*128 + c]; }
        const float invn = 1.f / (float)(NATOMS * MNBR);
        float mean = Sa * invn;
        float var  = Qa * invn - mean*mean;
        float inv  = scale[c] * rsqrtf(var + EPSBN);
        prm1[c]       = inv;
        prm1[128 + c] = offset[c] - mean*inv;       // folded offset
    }
}

// ---------------- kernel 4: main pass ----------------
__global__ __launch_bounds__(256, 4) void k_mainm(
    const int* __restrict__ nbr, const float* __restrict__ atomF,
    const float* __restrict__ bond, const unsigned short* __restrict__ Wpk,
    const float* __restrict__ Pself, const float* __restrict__ prm1,
    float* __restrict__ summed, float* __restrict__ partial2)
{
    __shared__ __align__(16) unsigned short A[48*AR];
    __shared__ float Y[12*66];                      // per-(m,g) gate partials
    __shared__ int   Ni[48];
    __shared__ float red[256];
    const int tid = threadIdx.x, w = tid >> 6, lane = tid & 63;
    const int g = lane >> 4, x = lane & 15;
    const int ch0 = w*16 + x;
    short8 B0[4], B1[4];
    #pragma unroll
    for (int ks = 0; ks < 4; ++ks) {
        B0[ks] = *(const short8*)(Wpk + ((w*4 + ks)*64 + lane)*8);
        B1[ks] = *(const short8*)(Wpk + (((w+4)*4 + ks)*64 + lane)*8);
    }
    const float iv0 = prm1[ch0],      of0 = prm1[C2F + ch0];
    const float iv1 = prm1[64 + ch0], of1 = prm1[C2F + 64 + ch0];
    for (int idx = tid; idx < 48*AR/2; idx += 256) ((unsigned int*)A)[idx] = 0u;
    float s2 = 0.f, q2 = 0.f;

    for (int grp = blockIdx.x; grp < GROUPS; grp += gridDim.x) {
        const int base = grp*4;
        __syncthreads();
        if (tid < 48) Ni[tid] = nbr[base*MNBR + tid];
        __syncthreads();
        #pragma unroll
        for (int it = 0; it < 6; ++it) {
            int idx = it*256 + tid;
            int p = idx >> 5, c = idx & 31;
            if (c < 16) {
                int r = Ni[p];
                float4 v = *(const float4*)(atomF + (size_t)r*FDIM + 4*c);
                uint2 u; u.x = pkbf(v.x, v.y); u.y = pkbf(v.z, v.w);
                *(uint2*)(A + p*AR + 4*c) = u;
            } else if (c < 27) {
                int cc = c - 16;
                int pa = p/12;
                const float* bp = bond + (size_t)(base + pa)*(MNBR*BDIM)
                                       + (p - pa*12)*BDIM + 4*cc;
                float b0 = bp[0], b1 = 0.f, b2 = 0.f, b3 = 0.f;
                if (cc < 10) { b1 = bp[1]; b2 = bp[2]; b3 = bp[3]; }
                uint2 u; u.x = pkbf(b0, b1); u.y = pkbf(b2, b3);
                *(uint2*)(A + p*AR + 64 + 4*cc) = u;
            }
        }
        __syncthreads();
        f32x4 z = {0.f, 0.f, 0.f, 0.f};
        f32x4 acc[3][2];
        #pragma unroll
        for (int m = 0; m < 3; ++m) { acc[m][0] = z; acc[m][1] = z; }
        #pragma unroll
        for (int ks = 0; ks < 4; ++ks) {
            #pragma unroll
            for (int m = 0; m < 3; ++m) {
                short8 a = *(const short8*)(A + (m*16 + x)*AR + ks*32 + g*8);
                acc[m][0] = __builtin_amdgcn_mfma_f32_16x16x32_bf16(a, B0[ks], acc[m][0], 0, 0, 0);
                acc[m][1] = __builtin_amdgcn_mfma_f32_16x16x32_bf16(a, B1[ks], acc[m][1], 0, 0, 0);
            }
        }
        #pragma unroll
        for (int m = 0; m < 3; ++m) {
            int ia = base + (m*16 + g*4)/12;        // uniform over rg
            float ps0 = Pself[(size_t)ia*C2F + ch0];
            float ps1 = Pself[(size_t)ia*C2F + 64 + ch0];
            float sY = 0.f;
            #pragma unroll
            for (int rg = 0; rg < 4; ++rg) {
                float y0 = (acc[m][0][rg] + ps0)*iv0 + of0;   // filter
                float y1 = (acc[m][1][rg] + ps1)*iv1 + of1;   // core
                sY += sigmoidf(y0) * softplusf(y1);
            }
            Y[(m*4 + g)*66 + ch0] = sY;             // atom = slot/3
        }
        __syncthreads();
        float sv = Y[(3*w)*66 + lane] + Y[(3*w + 1)*66 + lane] + Y[(3*w + 2)*66 + lane];
        summed[(size_t)(base + w)*FDIM + lane] = sv;
        s2 += sv; q2 = fmaf(sv, sv, q2);
    }
    red[tid] = s2; __syncthreads();
    if (tid < 64) partial2[blockIdx.x*128 + tid]
        = red[tid] + red[tid+64] + red[tid+128] + red[tid+192];
    __syncthreads();
    red[tid] = q2; __syncthreads();
    if (tid < 64) partial2[blockIdx.x*128 + 64 + tid]
        = red[tid] + red[tid+64] + red[tid+128] + red[tid+192];
}

// ---------------- kernel 5: finalize BN2 params ----------------
__global__ __launch_bounds__(1024) void k_bn2_finalize(
    const float* __restrict__ red2, const float* __restrict__ scale,
    const float* __restrict__ offset, float* __restrict__ prm2)
{
    __shared__ float redS[1024], redQ[1024];
    const int tid = threadIdx.x, f = tid & 63, h = tid >> 6;    // 16 slices
    float S = 0.f, Q = 0.f;
    for (int blk = h; blk < 128; blk += 16) {
        S += red2[blk*128 + f];
        Q += red2[blk*128 + 64 + f];
    }
    redS[tid] = S; redQ[tid] = Q;
    __syncthreads();
    if (tid < 64) {
        float Sa = 0.f, Qa = 0.f;
        #pragma unroll
        for (int hh = 0; hh < 16; ++hh) { Sa += redS[hh*64 + f]; Qa += redQ[hh*64 + f]; }
        const float invn = 1.f / (float)NATOMS;
        float mean = Sa * invn;
        float var  = Qa * invn - mean*mean;
        float inv  = scale[f] * rsqrtf(var + EPSBN);
        prm2[f]      = inv;
        prm2[64 + f] = offset[f] - mean*inv;
    }
}

// ---------------- kernel 6: residual + softplus ----------------
__global__ __launch_bounds__(256) void k_final(
    const float* __restrict__ atomF, const float* __restrict__ summed,
    const float* __restrict__ prm2, float* __restrict__ out)
{
    __shared__ float iv[64], of[64];
    if (threadIdx.x < 64) {
        iv[threadIdx.x] = prm2[threadIdx.x];
        of[threadIdx.x] = prm2[64 + threadIdx.x];
    }
    __syncthreads();
    const int total4 = NATOMS*FDIM/4;
    for (int t = blockIdx.x*blockDim.x + threadIdx.x; t < total4;
         t += gridDim.x*blockDim.x) {
        float4 a = ((const float4*)atomF)[t];
        float4 s = ((const float4*)summed)[t];
        int fb = (t*4) & 63;
        float4 r;
        r.x = softplusf(a.x + s.x*iv[fb]   + of[fb]);
        r.y = softplusf(a.y + s.y*iv[fb+1] + of[fb+1]);
        r.z = softplusf(a.z + s.z*iv[fb+2] + of[fb+2]);
        r.w = softplusf(a.w + s.w*iv[fb+3] + of[fb+3]);
        ((float4*)out)[t] = r;
    }
}

extern "C" void kernel_launch(void* const* d_in, const int* in_sizes, int n_in,
                              void* d_out, int out_size, void* d_ws, size_t ws_size,
                              hipStream_t stream)
{
    const int*   nbr   = (const int*)  d_in[0];
    const float* atomF = (const float*)d_in[1];
    const float* bond  = (const float*)d_in[2];
    const float* W     = (const float*)d_in[3];
    // d_in[4] = b: cancels through BN1 (shift invariance) -> unused
    const float* s1    = (const float*)d_in[5];
    const float* o1    = (const float*)d_in[6];
    const float* s2    = (const float*)d_in[7];
    const float* o2    = (const float*)d_in[8];
    float* out = (float*)d_out;

    float* fws      = (float*)d_ws;
    float* Pself    = fws;                                   // N*128
    float* summed   = Pself    + (size_t)NATOMS*C2F;         // N*64
    float* partial1 = summed   + (size_t)NATOMS*FDIM;        // 2048*256
    float* partial2 = partial1 + (size_t)NBLK*256;           // 2048*128
    float* red1     = partial2 + (size_t)NBLK*128;           // 128*256
    float* red2     = red1     + 128*256;                    // 128*128
    float* prm1     = red2     + 128*128;                    // 256
    float* prm2     = prm1     + 256;                        // 128
    unsigned short* Wsn = (unsigned short*)(prm2 + 128);     // 8192 shorts
    unsigned short* Wpk = Wsn + 8192;                        // 16384 shorts

    hipLaunchKernelGGL(k_pack,         dim3(64),   dim3(256),  0, stream, W, Wsn, Wpk);
    hipLaunchKernelGGL(k_proj,         dim3(782),  dim3(256),  0, stream, atomF, Wsn, Pself);
    hipLaunchKernelGGL(k_stats,        dim3(NBLK), dim3(256),  0, stream,
                       nbr, atomF, bond, Wpk, Pself, partial1);
    hipLaunchKernelGGL(k_red,          dim3(128),  dim3(256),  0, stream, partial1, red1, 256);
    hipLaunchKernelGGL(k_bn1_finalize, dim3(1),    dim3(1024), 0, stream, red1, s1, o1, prm1);
    hipLaunchKernelGGL(k_mainm,        dim3(NBLK), dim3(256),  0, stream,
                       nbr, atomF, bond, Wpk, Pself, prm1, summed, partial2);
    hipLaunchKernelGGL(k_red,          dim3(128),  dim3(256),  0, stream, partial2, red2, 128);
    hipLaunchKernelGGL(k_bn2_finalize, dim3(1),    dim3(1024), 0, stream, red2, s2, o2, prm2);
    hipLaunchKernelGGL(k_final,        dim3(2048), dim3(256),  0, stream, atomF, summed, prm2, out);
}

// Round 7
// 397.252 us; speedup vs baseline: 10.2348x; 1.1963x over previous
//
#include <hip/hip_runtime.h>
#include <hip/hip_bf16.h>
#include <math.h>

// CGConv: N=100000 atoms, M=12 nbrs, F=64 atom-feat, B=41 bond-feat
// gated = [self | nbr | bond] @ W + b ; BN1 over N*M rows ;
// summed = sum_j sigmoid(filter)*softplus(core) ; BN2 over N rows ;
// out = softplus(atom + summed_bn)
//
// R7: kill the double pair-pass. The pair GEMM runs ONCE (k_gemm): MFMA
// computes gated, accumulates BN1 stats, and stores gated bf16 (307MB) in
// MFMA-fragment layout (uint4/lane, fully coalesced). k_apply then streams
// gated back (no gather, no staging, no MFMA), applies BN1+gate, nbr-sums.
// Cross-term analysis shows BN1 sumsq cannot be decomposed algebraically
// (Sum v_r*w_ij is irreducibly per-pair) -> two phases are forced, but the
// recompute is not.
// Pself stored bf16 (only k_gemm reads it). bias b cancels through BN1.

#define NATOMS  100000
#define MNBR    12
#define FDIM    64
#define BDIM    41
#define C2F     128
#define EPSBN   1e-5f
#define NBLK    2048              // pair-kernel grid (= #partial slots)
#define GROUPS  (NATOMS/4)        // 25000 groups of 4 atoms = 48 pairs
#define AR      136               // pair A-tile row stride (shorts)
#define PR      72                // proj A-tile row stride (shorts)

typedef __attribute__((ext_vector_type(8))) short  short8;   // bf16 x8 frag
typedef __attribute__((ext_vector_type(4))) float  f32x4;    // C/D frag

__device__ __forceinline__ float softplusf(float x) {
    return fmaxf(x, 0.f) + __logf(1.f + __expf(-fabsf(x)));
}
__device__ __forceinline__ float sigmoidf(float x) {
    return 1.f / (1.f + __expf(-x));
}
__device__ __forceinline__ unsigned short f2bf(float f) {   // pack kernel only
    unsigned int x = __builtin_bit_cast(unsigned int, f);
    unsigned int r = (x + 0x7fff + ((x >> 16) & 1)) >> 16;  // RNE
    return (unsigned short)r;
}
__device__ __forceinline__ unsigned int pkbf(float a, float b) {
    unsigned short lo = __builtin_bit_cast(unsigned short, __float2bfloat16(a));
    unsigned short hi = __builtin_bit_cast(unsigned short, __float2bfloat16(b));
    return (unsigned)lo | ((unsigned)hi << 16);
}
__device__ __forceinline__ float bflo(unsigned int u) {     // low bf16 -> f32
    return __builtin_bit_cast(float, u << 16);
}
__device__ __forceinline__ float bfhi(unsigned int u) {     // high bf16 -> f32
    return __builtin_bit_cast(float, u & 0xffff0000u);
}
__device__ __forceinline__ float bf2f(unsigned short u) {
    return __builtin_bit_cast(float, ((unsigned int)u) << 16);
}

// ---------------- kernel 0: prepack W fragments ----------------
// Wsn: self rows,  [n<8][ks<2][lane][e], k = ks*32+(lane>>4)*8+e, col=n*16+(lane&15)
// Wpk: nbr+bond rows, [n<8][ks<4][lane][e]; k<105 -> W[64+k][col] else 0
__global__ __launch_bounds__(256) void k_pack(
    const float* __restrict__ W,
    unsigned short* __restrict__ Wsn, unsigned short* __restrict__ Wpk)
{
    const int t0 = blockIdx.x*256 + threadIdx.x;
    for (int idx = t0; idx < 8*2*64*8; idx += gridDim.x*256) {
        int e = idx & 7, lane = (idx >> 3) & 63, ks = (idx >> 9) & 1, n = idx >> 10;
        int k   = ks*32 + (lane >> 4)*8 + e;
        int col = n*16 + (lane & 15);
        Wsn[idx] = f2bf(W[k*C2F + col]);
    }
    for (int idx = t0; idx < 8*4*64*8; idx += gridDim.x*256) {
        int e = idx & 7, lane = (idx >> 3) & 63, ks = (idx >> 9) & 3, n = idx >> 11;
        int k   = ks*32 + (lane >> 4)*8 + e;
        int col = n*16 + (lane & 15);
        float v = (k < 105) ? W[(64 + k)*C2F + col] : 0.f;
        Wpk[idx] = f2bf(v);
    }
}

// ---------------- kernel 1: Pself = atom @ W_self (MFMA, bf16 out) ----------------
__global__ __launch_bounds__(256, 4) void k_proj(
    const float* __restrict__ atomF, const unsigned short* __restrict__ Wsn,
    unsigned short* __restrict__ PselfBf)
{
    __shared__ __align__(16) unsigned short A[64*PR];
    const int tid = threadIdx.x, w = tid >> 6, lane = tid & 63;
    const int g = lane >> 4, x = lane & 15;
    short8 B0[2], B1[2];
    #pragma unroll
    for (int ks = 0; ks < 2; ++ks) {
        B0[ks] = *(const short8*)(Wsn + ((w*2 + ks)*64 + lane)*8);
        B1[ks] = *(const short8*)(Wsn + (((w+4)*2 + ks)*64 + lane)*8);
    }
    for (int a0 = blockIdx.x*64; a0 < NATOMS; a0 += gridDim.x*64) {
        __syncthreads();
        #pragma unroll
        for (int it = 0; it < 4; ++it) {
            int idx = it*256 + tid;
            int p = idx >> 4, c = idx & 15;
            int i = a0 + p;
            float4 v = make_float4(0.f, 0.f, 0.f, 0.f);
            if (i < NATOMS) v = *(const float4*)(atomF + (size_t)i*FDIM + 4*c);
            uint2 u; u.x = pkbf(v.x, v.y); u.y = pkbf(v.z, v.w);
            *(uint2*)(A + p*PR + 4*c) = u;
        }
        __syncthreads();
        f32x4 z = {0.f, 0.f, 0.f, 0.f};
        f32x4 acc[4][2];
        #pragma unroll
        for (int m = 0; m < 4; ++m) { acc[m][0] = z; acc[m][1] = z; }
        #pragma unroll
        for (int ks = 0; ks < 2; ++ks) {
            #pragma unroll
            for (int m = 0; m < 4; ++m) {
                short8 a = *(const short8*)(A + (m*16 + x)*PR + ks*32 + g*8);
                acc[m][0] = __builtin_amdgcn_mfma_f32_16x16x32_bf16(a, B0[ks], acc[m][0], 0, 0, 0);
                acc[m][1] = __builtin_amdgcn_mfma_f32_16x16x32_bf16(a, B1[ks], acc[m][1], 0, 0, 0);
            }
        }
        #pragma unroll
        for (int m = 0; m < 4; ++m) {
            int i = a0 + m*16 + g*4;
            #pragma unroll
            for (int rg = 0; rg < 4; ++rg) {
                if (i + rg < NATOMS) {
                    PselfBf[(size_t)(i+rg)*C2F + w*16 + x]     = f2bf(acc[m][0][rg]);
                    PselfBf[(size_t)(i+rg)*C2F + (w+4)*16 + x] = f2bf(acc[m][1][rg]);
                }
            }
        }
    }
}

// ---------------- kernel 2: pair GEMM + BN1 stats + gated store ----------------
// A rows = [nbr(64) | bond(41) | pad] bf16, K=128 (4 ksteps), M=48 pairs.
// Wave w owns n-tiles {w, w+4}: filter ch f=w*16+x and core ch f+64 in same lane.
// gated stored as uint4/lane/m in fragment layout:
//   idx16B = ((grp*4 + w)*3 + m)*64 + lane
__global__ __launch_bounds__(256, 4) void k_gemm(
    const int* __restrict__ nbr, const float* __restrict__ atomF,
    const float* __restrict__ bond, const unsigned short* __restrict__ Wpk,
    const unsigned short* __restrict__ PselfBf,
    uint4* __restrict__ gated, float* __restrict__ partial1)
{
    __shared__ __align__(16) unsigned short A[48*AR];
    __shared__ int Ni[48];
    const int tid = threadIdx.x, w = tid >> 6, lane = tid & 63;
    const int g = lane >> 4, x = lane & 15;
    const int ch0 = w*16 + x;
    short8 B0[4], B1[4];
    #pragma unroll
    for (int ks = 0; ks < 4; ++ks) {
        B0[ks] = *(const short8*)(Wpk + ((w*4 + ks)*64 + lane)*8);
        B1[ks] = *(const short8*)(Wpk + (((w+4)*4 + ks)*64 + lane)*8);
    }
    for (int idx = tid; idx < 48*AR/2; idx += 256) ((unsigned int*)A)[idx] = 0u;
    float s0 = 0.f, q0 = 0.f, s1 = 0.f, q1 = 0.f;

    for (int grp = blockIdx.x; grp < GROUPS; grp += gridDim.x) {
        const int base = grp*4;
        __syncthreads();
        if (tid < 48) Ni[tid] = nbr[base*MNBR + tid];
        __syncthreads();
        #pragma unroll
        for (int it = 0; it < 6; ++it) {
            int idx = it*256 + tid;
            int p = idx >> 5, c = idx & 31;
            if (c < 16) {
                int r = Ni[p];
                float4 v = *(const float4*)(atomF + (size_t)r*FDIM + 4*c);
                uint2 u; u.x = pkbf(v.x, v.y); u.y = pkbf(v.z, v.w);
                *(uint2*)(A + p*AR + 4*c) = u;
            } else if (c < 27) {
                int cc = c - 16;
                int pa = p/12;
                const float* bp = bond + (size_t)(base + pa)*(MNBR*BDIM)
                                       + (p - pa*12)*BDIM + 4*cc;
                float b0 = bp[0], b1 = 0.f, b2 = 0.f, b3 = 0.f;
                if (cc < 10) { b1 = bp[1]; b2 = bp[2]; b3 = bp[3]; }
                uint2 u; u.x = pkbf(b0, b1); u.y = pkbf(b2, b3);
                *(uint2*)(A + p*AR + 64 + 4*cc) = u;
            }
        }
        __syncthreads();
        f32x4 z = {0.f, 0.f, 0.f, 0.f};
        f32x4 acc[3][2];
        #pragma unroll
        for (int m = 0; m < 3; ++m) { acc[m][0] = z; acc[m][1] = z; }
        #pragma unroll
        for (int ks = 0; ks < 4; ++ks) {
            #pragma unroll
            for (int m = 0; m < 3; ++m) {
                short8 a = *(const short8*)(A + (m*16 + x)*AR + ks*32 + g*8);
                acc[m][0] = __builtin_amdgcn_mfma_f32_16x16x32_bf16(a, B0[ks], acc[m][0], 0, 0, 0);
                acc[m][1] = __builtin_amdgcn_mfma_f32_16x16x32_bf16(a, B1[ks], acc[m][1], 0, 0, 0);
            }
        }
        uint4* gbase = gated + ((size_t)grp*4 + w)*3*64 + lane;
        #pragma unroll
        for (int m = 0; m < 3; ++m) {
            int ia = base + (m*16 + g*4)/12;       // uniform over rg (proven)
            float ps0 = bf2f(PselfBf[(size_t)ia*C2F + ch0]);
            float ps1 = bf2f(PselfBf[(size_t)ia*C2F + 64 + ch0]);
            float v00 = acc[m][0][0] + ps0, v01 = acc[m][0][1] + ps0;
            float v02 = acc[m][0][2] + ps0, v03 = acc[m][0][3] + ps0;
            float v10 = acc[m][1][0] + ps1, v11 = acc[m][1][1] + ps1;
            float v12 = acc[m][1][2] + ps1, v13 = acc[m][1][3] + ps1;
            s0 += (v00 + v01) + (v02 + v03);
            s1 += (v10 + v11) + (v12 + v13);
            q0 = fmaf(v00, v00, q0); q0 = fmaf(v01, v01, q0);
            q0 = fmaf(v02, v02, q0); q0 = fmaf(v03, v03, q0);
            q1 = fmaf(v10, v10, q1); q1 = fmaf(v11, v11, q1);
            q1 = fmaf(v12, v12, q1); q1 = fmaf(v13, v13, q1);
            uint4 pk;
            pk.x = pkbf(v00, v01); pk.y = pkbf(v02, v03);
            pk.z = pkbf(v10, v11); pk.w = pkbf(v12, v13);
            gbase[m*64] = pk;
        }
    }
    s0 += __shfl_xor(s0, 16); s0 += __shfl_xor(s0, 32);
    s1 += __shfl_xor(s1, 16); s1 += __shfl_xor(s1, 32);
    q0 += __shfl_xor(q0, 16); q0 += __shfl_xor(q0, 32);
    q1 += __shfl_xor(q1, 16); q1 += __shfl_xor(q1, 32);
    if (g == 0) {
        float* pb = partial1 + blockIdx.x*256;     // {sum[128], sumsq[128]}
        pb[ch0]            = s0; pb[64 + ch0]        = s1;
        pb[C2F + ch0]      = q0; pb[C2F + 64 + ch0]  = q1;
    }
}

// ---------------- kernel: partial reduce 2048 -> 128 slots ----------------
__global__ __launch_bounds__(256) void k_red(
    const float* __restrict__ in, float* __restrict__ outp, int width)
{
    const int b = blockIdx.x;                       // 128 blocks x 16 slots
    for (int c = threadIdx.x; c < width; c += 256) {
        float s = 0.f;
        #pragma unroll 4
        for (int k = 0; k < 16; ++k) s += in[(size_t)(b*16 + k)*width + c];
        outp[(size_t)b*width + c] = s;
    }
}

// ---------------- kernel 3: finalize BN1 params ----------------
__global__ __launch_bounds__(1024) void k_bn1_finalize(
    const float* __restrict__ red1, const float* __restrict__ scale,
    const float* __restrict__ offset, float* __restrict__ prm1)
{
    __shared__ float redS[1024], redQ[1024];
    const int tid = threadIdx.x, c = tid & 127, h = tid >> 7;   // 8 slices
    float S = 0.f, Q = 0.f;
    for (int blk = h; blk < 128; blk += 8) {
        S += red1[blk*256 + c];
        Q += red1[blk*256 + 128 + c];
    }
    redS[tid] = S; redQ[tid] = Q;
    __syncthreads();
    if (tid < 128) {
        float Sa = 0.f, Qa = 0.f;
        #pragma unroll
        for (int hh = 0; hh < 8; ++hh) { Sa += redS[hh*128 + c]; Qa += redQ[hh*128 + c]; }
        const float invn = 1.f / (float)(NATOMS * MNBR);
        float mean = Sa * invn;
        float var  = Qa * invn - mean*mean;
        float inv  = scale[c] * rsqrtf(var + EPSBN);
        prm1[c]       = inv;
        prm1[128 + c] = offset[c] - mean*inv;       // folded offset
    }
}

// ---------------- kernel 4: apply pass (stream gated, gate, nbr-sum) ----------------
__global__ __launch_bounds__(256, 8) void k_apply(
    const uint4* __restrict__ gated, const float* __restrict__ prm1,
    float* __restrict__ summed, float* __restrict__ partial2)
{
    __shared__ float Y[12*66];                      // per-(4m+g) gate partials
    __shared__ float red[256];
    const int tid = threadIdx.x, w = tid >> 6, lane = tid & 63;
    const int g = lane >> 4, x = lane & 15;
    const int ch0 = w*16 + x;
    const float iv0 = prm1[ch0],      of0 = prm1[C2F + ch0];
    const float iv1 = prm1[64 + ch0], of1 = prm1[C2F + 64 + ch0];
    float s2 = 0.f, q2 = 0.f;

    for (int grp = blockIdx.x; grp < GROUPS; grp += gridDim.x) {
        __syncthreads();                            // protect Y reuse
        const uint4* gbase = gated + ((size_t)grp*4 + w)*3*64 + lane;
        #pragma unroll
        for (int m = 0; m < 3; ++m) {
            uint4 pk = gbase[m*64];
            float y00 = bflo(pk.x)*iv0 + of0, y01 = bfhi(pk.x)*iv0 + of0;
            float y02 = bflo(pk.y)*iv0 + of0, y03 = bfhi(pk.y)*iv0 + of0;
            float y10 = bflo(pk.z)*iv1 + of1, y11 = bfhi(pk.z)*iv1 + of1;
            float y12 = bflo(pk.w)*iv1 + of1, y13 = bfhi(pk.w)*iv1 + of1;
            float sY = sigmoidf(y00)*softplusf(y10) + sigmoidf(y01)*softplusf(y11)
                     + sigmoidf(y02)*softplusf(y12) + sigmoidf(y03)*softplusf(y13);
            Y[(m*4 + g)*66 + ch0] = sY;             // atom = (4m+g)/3
        }
        __syncthreads();
        float sv = Y[(3*w)*66 + lane] + Y[(3*w + 1)*66 + lane] + Y[(3*w + 2)*66 + lane];
        summed[(size_t)(grp*4 + w)*FDIM + lane] = sv;
        s2 += sv; q2 = fmaf(sv, sv, q2);
    }
    red[tid] = s2; __syncthreads();
    if (tid < 64) partial2[blockIdx.x*128 + tid]
        = red[tid] + red[tid+64] + red[tid+128] + red[tid+192];
    __syncthreads();
    red[tid] = q2; __syncthreads();
    if (tid < 64) partial2[blockIdx.x*128 + 64 + tid]
        = red[tid] + red[tid+64] + red[tid+128] + red[tid+192];
}

// ---------------- kernel 5: finalize BN2 params ----------------
__global__ __launch_bounds__(1024) void k_bn2_finalize(
    const float* __restrict__ red2, const float* __restrict__ scale,
    const float* __restrict__ offset, float* __restrict__ prm2)
{
    __shared__ float redS[1024], redQ[1024];
    const int tid = threadIdx.x, f = tid & 63, h = tid >> 6;    // 16 slices
    float S = 0.f, Q = 0.f;
    for (int blk = h; blk < 128; blk += 16) {
        S += red2[blk*128 + f];
        Q += red2[blk*128 + 64 + f];
    }
    redS[tid] = S; redQ[tid] = Q;
    __syncthreads();
    if (tid < 64) {
        float Sa = 0.f, Qa = 0.f;
        #pragma unroll
        for (int hh = 0; hh < 16; ++hh) { Sa += redS[hh*64 + f]; Qa += redQ[hh*64 + f]; }
        const float invn = 1.f / (float)NATOMS;
        float mean = Sa * invn;
        float var  = Qa * invn - mean*mean;
        float inv  = scale[f] * rsqrtf(var + EPSBN);
        prm2[f]      = inv;
        prm2[64 + f] = offset[f] - mean*inv;
    }
}

// ---------------- kernel 6: residual + softplus ----------------
__global__ __launch_bounds__(256) void k_final(
    const float* __restrict__ atomF, const float* __restrict__ summed,
    const float* __restrict__ prm2, float* __restrict__ out)
{
    __shared__ float iv[64], of[64];
    if (threadIdx.x < 64) {
        iv[threadIdx.x] = prm2[threadIdx.x];
        of[threadIdx.x] = prm2[64 + threadIdx.x];
    }
    __syncthreads();
    const int total4 = NATOMS*FDIM/4;
    for (int t = blockIdx.x*blockDim.x + threadIdx.x; t < total4;
         t += gridDim.x*blockDim.x) {
        float4 a = ((const float4*)atomF)[t];
        float4 s = ((const float4*)summed)[t];
        int fb = (t*4) & 63;
        float4 r;
        r.x = softplusf(a.x + s.x*iv[fb]   + of[fb]);
        r.y = softplusf(a.y + s.y*iv[fb+1] + of[fb+1]);
        r.z = softplusf(a.z + s.z*iv[fb+2] + of[fb+2]);
        r.w = softplusf(a.w + s.w*iv[fb+3] + of[fb+3]);
        ((float4*)out)[t] = r;
    }
}

extern "C" void kernel_launch(void* const* d_in, const int* in_sizes, int n_in,
                              void* d_out, int out_size, void* d_ws, size_t ws_size,
                              hipStream_t stream)
{
    const int*   nbr   = (const int*)  d_in[0];
    const float* atomF = (const float*)d_in[1];
    const float* bond  = (const float*)d_in[2];
    const float* W     = (const float*)d_in[3];
    // d_in[4] = b: cancels through BN1 (shift invariance) -> unused
    const float* s1    = (const float*)d_in[5];
    const float* o1    = (const float*)d_in[6];
    const float* s2    = (const float*)d_in[7];
    const float* o2    = (const float*)d_in[8];
    float* out = (float*)d_out;

    // ws layout (~362 MB total)
    uint4* gated        = (uint4*)d_ws;                          // GROUPS*12*64*16B = 307.2MB
    unsigned short* PselfBf = (unsigned short*)(gated + (size_t)GROUPS*12*64);  // N*128 bf16
    float* summed   = (float*)(PselfBf + (size_t)NATOMS*C2F);    // N*64 f32
    float* partial1 = summed   + (size_t)NATOMS*FDIM;            // 2048*256
    float* partial2 = partial1 + (size_t)NBLK*256;               // 2048*128
    float* red1     = partial2 + (size_t)NBLK*128;               // 128*256
    float* red2     = red1     + 128*256;                        // 128*128
    float* prm1     = red2     + 128*128;                        // 256
    float* prm2     = prm1     + 256;                            // 128
    unsigned short* Wsn = (unsigned short*)(prm2 + 128);         // 8192 shorts
    unsigned short* Wpk = Wsn + 8192;                            // 16384 shorts

    hipLaunchKernelGGL(k_pack,         dim3(64),   dim3(256),  0, stream, W, Wsn, Wpk);
    hipLaunchKernelGGL(k_proj,         dim3(782),  dim3(256),  0, stream, atomF, Wsn, PselfBf);
    hipLaunchKernelGGL(k_gemm,         dim3(NBLK), dim3(256),  0, stream,
                       nbr, atomF, bond, Wpk, PselfBf, gated, partial1);
    hipLaunchKernelGGL(k_red,          dim3(128),  dim3(256),  0, stream, partial1, red1, 256);
    hipLaunchKernelGGL(k_bn1_finalize, dim3(1),    dim3(1024), 0, stream, red1, s1, o1, prm1);
    hipLaunchKernelGGL(k_apply,        dim3(NBLK), dim3(256),  0, stream,
                       gated, prm1, summed, partial2);
    hipLaunchKernelGGL(k_red,          dim3(128),  dim3(256),  0, stream, partial2, red2, 128);
    hipLaunchKernelGGL(k_bn2_finalize, dim3(1),    dim3(1024), 0, stream, red2, s2, o2, prm2);
    hipLaunchKernelGGL(k_final,        dim3(2048), dim3(256),  0, stream, atomF, summed, prm2, out);
}

// Round 8
// 394.187 us; speedup vs baseline: 10.3144x; 1.0078x over previous
//
#include <hip/hip_runtime.h>
#include <hip/hip_bf16.h>
#include <math.h>

// CGConv: N=100000 atoms, M=12 nbrs, F=64 atom-feat, B=41 bond-feat
// gated = [self | nbr | bond] @ W + b ; BN1 over N*M rows ;
// summed = sum_j sigmoid(filter)*softplus(core) ; BN2 over N rows ;
// out = softplus(atom + summed_bn)
//
// R8: latency fix for k_gemm (was 72% of runtime, all pipes <20% busy).
//  - double-buffered LDS A-tile; group t+1's global loads issued into
//    registers BEFORE the MFMA cluster of group t (T14 async-stage split),
//    written to the alternate buffer after the epilogue. 1 barrier/group.
//  - Ni LDS staging dropped: staging threads load nbr[] directly
//    (broadcast-coalesced), killing a barrier + the Ni->gather dep chain.
//  - atomF pre-packed to bf16 (atomBf, by k_proj, bit-identical to the
//    previous in-kernel pack) -> gather is 8B/slot, zero conversion VALU.
// Two-phase structure (stats then apply) remains forced: BN1's sumsq
// cross-term Sum v_r*w_ij is irreducibly per-pair.

#define NATOMS  100000
#define MNBR    12
#define FDIM    64
#define BDIM    41
#define C2F     128
#define EPSBN   1e-5f
#define NBLK    2048              // pair-kernel grid (= #partial slots)
#define GROUPS  (NATOMS/4)        // 25000 groups of 4 atoms = 48 pairs
#define AR      136               // pair A-tile row stride (shorts)
#define PR      72                // proj A-tile row stride (shorts)

typedef __attribute__((ext_vector_type(8))) short  short8;   // bf16 x8 frag
typedef __attribute__((ext_vector_type(4))) float  f32x4;    // C/D frag

__device__ __forceinline__ float softplusf(float x) {
    return fmaxf(x, 0.f) + __logf(1.f + __expf(-fabsf(x)));
}
__device__ __forceinline__ float sigmoidf(float x) {
    return 1.f / (1.f + __expf(-x));
}
__device__ __forceinline__ unsigned short f2bf(float f) {   // pack kernel only
    unsigned int x = __builtin_bit_cast(unsigned int, f);
    unsigned int r = (x + 0x7fff + ((x >> 16) & 1)) >> 16;  // RNE
    return (unsigned short)r;
}
__device__ __forceinline__ unsigned int pkbf(float a, float b) {
    unsigned short lo = __builtin_bit_cast(unsigned short, __float2bfloat16(a));
    unsigned short hi = __builtin_bit_cast(unsigned short, __float2bfloat16(b));
    return (unsigned)lo | ((unsigned)hi << 16);
}
__device__ __forceinline__ float bflo(unsigned int u) {
    return __builtin_bit_cast(float, u << 16);
}
__device__ __forceinline__ float bfhi(unsigned int u) {
    return __builtin_bit_cast(float, u & 0xffff0000u);
}
__device__ __forceinline__ float bf2f(unsigned short u) {
    return __builtin_bit_cast(float, ((unsigned int)u) << 16);
}

// ---------------- kernel 0: prepack W fragments ----------------
__global__ __launch_bounds__(256) void k_pack(
    const float* __restrict__ W,
    unsigned short* __restrict__ Wsn, unsigned short* __restrict__ Wpk)
{
    const int t0 = blockIdx.x*256 + threadIdx.x;
    for (int idx = t0; idx < 8*2*64*8; idx += gridDim.x*256) {
        int e = idx & 7, lane = (idx >> 3) & 63, ks = (idx >> 9) & 1, n = idx >> 10;
        int k   = ks*32 + (lane >> 4)*8 + e;
        int col = n*16 + (lane & 15);
        Wsn[idx] = f2bf(W[k*C2F + col]);
    }
    for (int idx = t0; idx < 8*4*64*8; idx += gridDim.x*256) {
        int e = idx & 7, lane = (idx >> 3) & 63, ks = (idx >> 9) & 3, n = idx >> 11;
        int k   = ks*32 + (lane >> 4)*8 + e;
        int col = n*16 + (lane & 15);
        float v = (k < 105) ? W[(64 + k)*C2F + col] : 0.f;
        Wpk[idx] = f2bf(v);
    }
}

// ---------------- kernel 1: Pself (MFMA) + atomBf pack ----------------
__global__ __launch_bounds__(256, 4) void k_proj(
    const float* __restrict__ atomF, const unsigned short* __restrict__ Wsn,
    unsigned short* __restrict__ PselfBf, unsigned short* __restrict__ atomBf)
{
    __shared__ __align__(16) unsigned short A[64*PR];
    const int tid = threadIdx.x, w = tid >> 6, lane = tid & 63;
    const int g = lane >> 4, x = lane & 15;
    short8 B0[2], B1[2];
    #pragma unroll
    for (int ks = 0; ks < 2; ++ks) {
        B0[ks] = *(const short8*)(Wsn + ((w*2 + ks)*64 + lane)*8);
        B1[ks] = *(const short8*)(Wsn + (((w+4)*2 + ks)*64 + lane)*8);
    }
    for (int a0 = blockIdx.x*64; a0 < NATOMS; a0 += gridDim.x*64) {
        __syncthreads();
        #pragma unroll
        for (int it = 0; it < 4; ++it) {
            int idx = it*256 + tid;
            int p = idx >> 4, c = idx & 15;
            int i = a0 + p;
            float4 v = make_float4(0.f, 0.f, 0.f, 0.f);
            if (i < NATOMS) v = *(const float4*)(atomF + (size_t)i*FDIM + 4*c);
            uint2 u; u.x = pkbf(v.x, v.y); u.y = pkbf(v.z, v.w);
            *(uint2*)(A + p*PR + 4*c) = u;
            if (i < NATOMS) *(uint2*)(atomBf + (size_t)i*FDIM + 4*c) = u;
        }
        __syncthreads();
        f32x4 z = {0.f, 0.f, 0.f, 0.f};
        f32x4 acc[4][2];
        #pragma unroll
        for (int m = 0; m < 4; ++m) { acc[m][0] = z; acc[m][1] = z; }
        #pragma unroll
        for (int ks = 0; ks < 2; ++ks) {
            #pragma unroll
            for (int m = 0; m < 4; ++m) {
                short8 a = *(const short8*)(A + (m*16 + x)*PR + ks*32 + g*8);
                acc[m][0] = __builtin_amdgcn_mfma_f32_16x16x32_bf16(a, B0[ks], acc[m][0], 0, 0, 0);
                acc[m][1] = __builtin_amdgcn_mfma_f32_16x16x32_bf16(a, B1[ks], acc[m][1], 0, 0, 0);
            }
        }
        #pragma unroll
        for (int m = 0; m < 4; ++m) {
            int i = a0 + m*16 + g*4;
            #pragma unroll
            for (int rg = 0; rg < 4; ++rg) {
                if (i + rg < NATOMS) {
                    PselfBf[(size_t)(i+rg)*C2F + w*16 + x]     = f2bf(acc[m][0][rg]);
                    PselfBf[(size_t)(i+rg)*C2F + (w+4)*16 + x] = f2bf(acc[m][1][rg]);
                }
            }
        }
    }
}

// ---------------- kernel 2: pair GEMM + BN1 stats + gated store ----------------
// A rows = [nbr(64) | bond(41) | pad] bf16, K=128 (4 ksteps), M=48 pairs.
// Double-buffered LDS; next group's loads prefetched to registers under MFMA.
__global__ __launch_bounds__(256, 4) void k_gemm(
    const int* __restrict__ nbr, const unsigned short* __restrict__ atomBf,
    const float* __restrict__ bond, const unsigned short* __restrict__ Wpk,
    const unsigned short* __restrict__ PselfBf,
    uint4* __restrict__ gated, float* __restrict__ partial1)
{
    __shared__ __align__(16) unsigned short A[2][48*AR];
    const int tid = threadIdx.x, w = tid >> 6, lane = tid & 63;
    const int g = lane >> 4, x = lane & 15;
    const int ch0 = w*16 + x;
    short8 B0[4], B1[4];
    #pragma unroll
    for (int ks = 0; ks < 4; ++ks) {
        B0[ks] = *(const short8*)(Wpk + ((w*4 + ks)*64 + lane)*8);
        B1[ks] = *(const short8*)(Wpk + (((w+4)*4 + ks)*64 + lane)*8);
    }
    // zero both buffers once (covers the k=105..127 pad region)
    for (int idx = tid; idx < 2*48*AR/2; idx += 256) ((unsigned int*)A)[idx] = 0u;

    // per-thread slot map: idx = it*256+tid, p = idx>>5 (pair), c = idx&31
    //  c<16   -> nbr-row quad (8B from atomBf[r])
    //  16..26 -> bond quad cc=c-16 (pack f32x4 -> 2x uint)
    uint2 st[6];
    float s0 = 0.f, q0 = 0.f, s1 = 0.f, q1 = 0.f;

#define LOADG(GRP)                                                            \
    {   const int base_ = (GRP)*4;                                            \
        _Pragma("unroll")                                                     \
        for (int it = 0; it < 6; ++it) {                                      \
            int idx = it*256 + tid;                                           \
            int p = idx >> 5, c = idx & 31;                                   \
            if (c < 16) {                                                     \
                int r = nbr[base_*MNBR + p];                                  \
                st[it] = *(const uint2*)(atomBf + ((size_t)r << 6) + 4*c);    \
            } else if (c < 27) {                                              \
                int cc = c - 16;                                              \
                int pa = p/12;                                                \
                const float* bp = bond + (size_t)(base_ + pa)*(MNBR*BDIM)     \
                                       + (p - pa*12)*BDIM + 4*cc;             \
                float b0 = bp[0], b1 = 0.f, b2 = 0.f, b3 = 0.f;               \
                if (cc < 10) { b1 = bp[1]; b2 = bp[2]; b3 = bp[3]; }          \
                st[it].x = pkbf(b0, b1); st[it].y = pkbf(b2, b3);             \
            }                                                                 \
        } }

#define WRITEA(BUF)                                                           \
    {   _Pragma("unroll")                                                     \
        for (int it = 0; it < 6; ++it) {                                      \
            int idx = it*256 + tid;                                           \
            int p = idx >> 5, c = idx & 31;                                   \
            if (c < 16)      *(uint2*)(&A[BUF][p*AR + 4*c]) = st[it];         \
            else if (c < 27) *(uint2*)(&A[BUF][p*AR + 64 + 4*(c-16)]) = st[it]; \
        } }

    int grp = blockIdx.x;
    int cur = 0;
    if (grp < GROUPS) { LOADG(grp); WRITEA(0); }
    for (; grp < GROUPS; grp += gridDim.x) {
        const int nxt = grp + gridDim.x;
        __syncthreads();                          // A[cur] staged & prior reads done
        if (nxt < GROUPS) LOADG(nxt);             // issue next-group loads (T14)
        f32x4 z = {0.f, 0.f, 0.f, 0.f};
        f32x4 acc[3][2];
        #pragma unroll
        for (int m = 0; m < 3; ++m) { acc[m][0] = z; acc[m][1] = z; }
        #pragma unroll
        for (int ks = 0; ks < 4; ++ks) {
            #pragma unroll
            for (int m = 0; m < 3; ++m) {
                short8 a = *(const short8*)(&A[cur][(m*16 + x)*AR + ks*32 + g*8]);
                acc[m][0] = __builtin_amdgcn_mfma_f32_16x16x32_bf16(a, B0[ks], acc[m][0], 0, 0, 0);
                acc[m][1] = __builtin_amdgcn_mfma_f32_16x16x32_bf16(a, B1[ks], acc[m][1], 0, 0, 0);
            }
        }
        const int base = grp*4;
        uint4* gbase = gated + ((size_t)grp*4 + w)*3*64 + lane;
        #pragma unroll
        for (int m = 0; m < 3; ++m) {
            int ia = base + (m*16 + g*4)/12;      // uniform over rg (proven)
            float ps0 = bf2f(PselfBf[(size_t)ia*C2F + ch0]);
            float ps1 = bf2f(PselfBf[(size_t)ia*C2F + 64 + ch0]);
            float v00 = acc[m][0][0] + ps0, v01 = acc[m][0][1] + ps0;
            float v02 = acc[m][0][2] + ps0, v03 = acc[m][0][3] + ps0;
            float v10 = acc[m][1][0] + ps1, v11 = acc[m][1][1] + ps1;
            float v12 = acc[m][1][2] + ps1, v13 = acc[m][1][3] + ps1;
            s0 += (v00 + v01) + (v02 + v03);
            s1 += (v10 + v11) + (v12 + v13);
            q0 = fmaf(v00, v00, q0); q0 = fmaf(v01, v01, q0);
            q0 = fmaf(v02, v02, q0); q0 = fmaf(v03, v03, q0);
            q1 = fmaf(v10, v10, q1); q1 = fmaf(v11, v11, q1);
            q1 = fmaf(v12, v12, q1); q1 = fmaf(v13, v13, q1);
            uint4 pk;
            pk.x = pkbf(v00, v01); pk.y = pkbf(v02, v03);
            pk.z = pkbf(v10, v11); pk.w = pkbf(v12, v13);
            gbase[m*64] = pk;
        }
        if (nxt < GROUPS) WRITEA(cur ^ 1);        // regs arrived; fill other buf
        cur ^= 1;
    }
#undef LOADG
#undef WRITEA
    s0 += __shfl_xor(s0, 16); s0 += __shfl_xor(s0, 32);
    s1 += __shfl_xor(s1, 16); s1 += __shfl_xor(s1, 32);
    q0 += __shfl_xor(q0, 16); q0 += __shfl_xor(q0, 32);
    q1 += __shfl_xor(q1, 16); q1 += __shfl_xor(q1, 32);
    if (g == 0) {
        float* pb = partial1 + blockIdx.x*256;     // {sum[128], sumsq[128]}
        pb[ch0]            = s0; pb[64 + ch0]        = s1;
        pb[C2F + ch0]      = q0; pb[C2F + 64 + ch0]  = q1;
    }
}

// ---------------- kernel: partial reduce 2048 -> 128 slots ----------------
__global__ __launch_bounds__(256) void k_red(
    const float* __restrict__ in, float* __restrict__ outp, int width)
{
    const int b = blockIdx.x;
    for (int c = threadIdx.x; c < width; c += 256) {
        float s = 0.f;
        #pragma unroll 4
        for (int k = 0; k < 16; ++k) s += in[(size_t)(b*16 + k)*width + c];
        outp[(size_t)b*width + c] = s;
    }
}

// ---------------- kernel 3: finalize BN1 params ----------------
__global__ __launch_bounds__(1024) void k_bn1_finalize(
    const float* __restrict__ red1, const float* __restrict__ scale,
    const float* __restrict__ offset, float* __restrict__ prm1)
{
    __shared__ float redS[1024], redQ[1024];
    const int tid = threadIdx.x, c = tid & 127, h = tid >> 7;   // 8 slices
    float S = 0.f, Q = 0.f;
    for (int blk = h; blk < 128; blk += 8) {
        S += red1[blk*256 + c];
        Q += red1[blk*256 + 128 + c];
    }
    redS[tid] = S; redQ[tid] = Q;
    __syncthreads();
    if (tid < 128) {
        float Sa = 0.f, Qa = 0.f;
        #pragma unroll
        for (int hh = 0; hh < 8; ++hh) { Sa += redS[hh*128 + c]; Qa += redQ[hh*128 + c]; }
        const float invn = 1.f / (float)(NATOMS * MNBR);
        float mean = Sa * invn;
        float var  = Qa * invn - mean*mean;
        float inv  = scale[c] * rsqrtf(var + EPSBN);
        prm1[c]       = inv;
        prm1[128 + c] = offset[c] - mean*inv;       // folded offset
    }
}

// ---------------- kernel 4: apply pass (stream gated, gate, nbr-sum) ----------------
__global__ __launch_bounds__(256, 8) void k_apply(
    const uint4* __restrict__ gated, const float* __restrict__ prm1,
    float* __restrict__ summed, float* __restrict__ partial2)
{
    __shared__ float Y[12*66];
    __shared__ float red[256];
    const int tid = threadIdx.x, w = tid >> 6, lane = tid & 63;
    const int g = lane >> 4, x = lane & 15;
    const int ch0 = w*16 + x;
    const float iv0 = prm1[ch0],      of0 = prm1[C2F + ch0];
    const float iv1 = prm1[64 + ch0], of1 = prm1[C2F + 64 + ch0];
    float s2 = 0.f, q2 = 0.f;

    for (int grp = blockIdx.x; grp < GROUPS; grp += gridDim.x) {
        __syncthreads();
        const uint4* gbase = gated + ((size_t)grp*4 + w)*3*64 + lane;
        #pragma unroll
        for (int m = 0; m < 3; ++m) {
            uint4 pk = gbase[m*64];
            float y00 = bflo(pk.x)*iv0 + of0, y01 = bfhi(pk.x)*iv0 + of0;
            float y02 = bflo(pk.y)*iv0 + of0, y03 = bfhi(pk.y)*iv0 + of0;
            float y10 = bflo(pk.z)*iv1 + of1, y11 = bfhi(pk.z)*iv1 + of1;
            float y12 = bflo(pk.w)*iv1 + of1, y13 = bfhi(pk.w)*iv1 + of1;
            float sY = sigmoidf(y00)*softplusf(y10) + sigmoidf(y01)*softplusf(y11)
                     + sigmoidf(y02)*softplusf(y12) + sigmoidf(y03)*softplusf(y13);
            Y[(m*4 + g)*66 + ch0] = sY;
        }
        __syncthreads();
        float sv = Y[(3*w)*66 + lane] + Y[(3*w + 1)*66 + lane] + Y[(3*w + 2)*66 + lane];
        summed[(size_t)(grp*4 + w)*FDIM + lane] = sv;
        s2 += sv; q2 = fmaf(sv, sv, q2);
    }
    red[tid] = s2; __syncthreads();
    if (tid < 64) partial2[blockIdx.x*128 + tid]
        = red[tid] + red[tid+64] + red[tid+128] + red[tid+192];
    __syncthreads();
    red[tid] = q2; __syncthreads();
    if (tid < 64) partial2[blockIdx.x*128 + 64 + tid]
        = red[tid] + red[tid+64] + red[tid+128] + red[tid+192];
}

// ---------------- kernel 5: finalize BN2 params ----------------
__global__ __launch_bounds__(1024) void k_bn2_finalize(
    const float* __restrict__ red2, const float* __restrict__ scale,
    const float* __restrict__ offset, float* __restrict__ prm2)
{
    __shared__ float redS[1024], redQ[1024];
    const int tid = threadIdx.x, f = tid & 63, h = tid >> 6;    // 16 slices
    float S = 0.f, Q = 0.f;
    for (int blk = h; blk < 128; blk += 16) {
        S += red2[blk*128 + f];
        Q += red2[blk*128 + 64 + f];
    }
    redS[tid] = S; redQ[tid] = Q;
    __syncthreads();
    if (tid < 64) {
        float Sa = 0.f, Qa = 0.f;
        #pragma unroll
        for (int hh = 0; hh < 16; ++hh) { Sa += redS[hh*64 + f]; Qa += redQ[hh*64 + f]; }
        const float invn = 1.f / (float)NATOMS;
        float mean = Sa * invn;
        float var  = Qa * invn - mean*mean;
        float inv  = scale[f] * rsqrtf(var + EPSBN);
        prm2[f]      = inv;
        prm2[64 + f] = offset[f] - mean*inv;
    }
}

// ---------------- kernel 6: residual + softplus ----------------
__global__ __launch_bounds__(256) void k_final(
    const float* __restrict__ atomF, const float* __restrict__ summed,
    const float* __restrict__ prm2, float* __restrict__ out)
{
    __shared__ float iv[64], of[64];
    if (threadIdx.x < 64) {
        iv[threadIdx.x] = prm2[threadIdx.x];
        of[threadIdx.x] = prm2[64 + threadIdx.x];
    }
    __syncthreads();
    const int total4 = NATOMS*FDIM/4;
    for (int t = blockIdx.x*blockDim.x + threadIdx.x; t < total4;
         t += gridDim.x*blockDim.x) {
        float4 a = ((const float4*)atomF)[t];
        float4 s = ((const float4*)summed)[t];
        int fb = (t*4) & 63;
        float4 r;
        r.x = softplusf(a.x + s.x*iv[fb]   + of[fb]);
        r.y = softplusf(a.y + s.y*iv[fb+1] + of[fb+1]);
        r.z = softplusf(a.z + s.z*iv[fb+2] + of[fb+2]);
        r.w = softplusf(a.w + s.w*iv[fb+3] + of[fb+3]);
        ((float4*)out)[t] = r;
    }
}

extern "C" void kernel_launch(void* const* d_in, const int* in_sizes, int n_in,
                              void* d_out, int out_size, void* d_ws, size_t ws_size,
                              hipStream_t stream)
{
    const int*   nbr   = (const int*)  d_in[0];
    const float* atomF = (const float*)d_in[1];
    const float* bond  = (const float*)d_in[2];
    const float* W     = (const float*)d_in[3];
    // d_in[4] = b: cancels through BN1 (shift invariance) -> unused
    const float* s1    = (const float*)d_in[5];
    const float* o1    = (const float*)d_in[6];
    const float* s2    = (const float*)d_in[7];
    const float* o2    = (const float*)d_in[8];
    float* out = (float*)d_out;

    // ws layout (~375 MB total)
    uint4* gated        = (uint4*)d_ws;                          // GROUPS*12*64*16B = 307.2MB
    unsigned short* PselfBf = (unsigned short*)(gated + (size_t)GROUPS*12*64);  // N*128 bf16
    unsigned short* atomBf  = PselfBf + (size_t)NATOMS*C2F;      // N*64 bf16
    float* summed   = (float*)(atomBf + (size_t)NATOMS*FDIM);    // N*64 f32
    float* partial1 = summed   + (size_t)NATOMS*FDIM;            // 2048*256
    float* partial2 = partial1 + (size_t)NBLK*256;               // 2048*128
    float* red1     = partial2 + (size_t)NBLK*128;               // 128*256
    float* red2     = red1     + 128*256;                        // 128*128
    float* prm1     = red2     + 128*128;                        // 256
    float* prm2     = prm1     + 256;                            // 128
    unsigned short* Wsn = (unsigned short*)(prm2 + 128);         // 8192 shorts
    unsigned short* Wpk = Wsn + 8192;                            // 16384 shorts

    hipLaunchKernelGGL(k_pack,         dim3(64),   dim3(256),  0, stream, W, Wsn, Wpk);
    hipLaunchKernelGGL(k_proj,         dim3(782),  dim3(256),  0, stream,
                       atomF, Wsn, PselfBf, atomBf);
    hipLaunchKernelGGL(k_gemm,         dim3(NBLK), dim3(256),  0, stream,
                       nbr, atomBf, bond, Wpk, PselfBf, gated, partial1);
    hipLaunchKernelGGL(k_red,          dim3(128),  dim3(256),  0, stream, partial1, red1, 256);
    hipLaunchKernelGGL(k_bn1_finalize, dim3(1),    dim3(1024), 0, stream, red1, s1, o1, prm1);
    hipLaunchKernelGGL(k_apply,        dim3(NBLK), dim3(256),  0, stream,
                       gated, prm1, summed, partial2);
    hipLaunchKernelGGL(k_red,          dim3(128),  dim3(256),  0, stream, partial2, red2, 128);
    hipLaunchKernelGGL(k_bn2_finalize, dim3(1),    dim3(1024), 0, stream, red2, s2, o2, prm2);
    hipLaunchKernelGGL(k_final,        dim3(2048), dim3(256),  0, stream, atomF, summed, prm2, out);
}